// Round 2
// baseline (1402.073 us; speedup 1.0000x reference)
//
#include <hip/hip_runtime.h>
#include <hip/hip_bf16.h>
#include <cstdint>

#define NNODE 100000
#define NEDGE 500000
#define FIN   128
#define FHID  256
#define FOUT  128

// ---------------------------------------------------------------- utilities

__global__ void zero_ints(int* __restrict__ p, int n) {
    int i = blockIdx.x * blockDim.x + threadIdx.x;
    if (i < n) p[i] = 0;
}

// count degrees per relation (grid.y = relation)
__global__ void degrees_kernel(const int* __restrict__ sb, const int* __restrict__ db,
                               const int* __restrict__ sr, const int* __restrict__ dr,
                               const int* __restrict__ sj, const int* __restrict__ dj,
                               int* __restrict__ cnt_src, int* __restrict__ cnt_dst) {
    int r = blockIdx.y;
    int e = blockIdx.x * blockDim.x + threadIdx.x;
    if (e >= NEDGE) return;
    const int* s = (r == 0) ? sb : (r == 1) ? sr : sj;
    const int* d = (r == 0) ? db : (r == 1) ? dr : dj;
    atomicAdd(&cnt_src[r * NNODE + s[e]], 1);
    atomicAdd(&cnt_dst[r * NNODE + d[e]], 1);
}

// c = rsqrt(max(deg,1))
__global__ void norms_kernel(const int* __restrict__ cnt_src, const int* __restrict__ cnt_dst,
                             float* __restrict__ c_src, float* __restrict__ c_dst) {
    int i = blockIdx.x * blockDim.x + threadIdx.x;
    if (i >= 3 * NNODE) return;
    c_src[i] = rsqrtf((float)max(cnt_src[i], 1));
    c_dst[i] = rsqrtf((float)max(cnt_dst[i], 1));
}

// -------- exclusive scan of cnt_dst -> row_ptr (3 relations, N=100000 each)
#define SCAN_TILE 1024
#define NB 98   // ceil(100000/1024)

__global__ void scan_phase1(const int* __restrict__ cnt_dst, int* __restrict__ rp,
                            int* __restrict__ bsum) {
    int r = blockIdx.y;
    int tid = threadIdx.x;
    int idx = blockIdx.x * SCAN_TILE + tid * 4;
    int v[4];
#pragma unroll
    for (int i = 0; i < 4; ++i)
        v[i] = (idx + i < NNODE) ? cnt_dst[r * NNODE + idx + i] : 0;
    int tsum = v[0] + v[1] + v[2] + v[3];
    __shared__ int sm[256];
    sm[tid] = tsum;
    __syncthreads();
    for (int off = 1; off < 256; off <<= 1) {
        int t = 0;
        if (tid >= off) t = sm[tid - off];
        __syncthreads();
        sm[tid] += t;
        __syncthreads();
    }
    int excl = sm[tid] - tsum;
    int run = excl;
#pragma unroll
    for (int i = 0; i < 4; ++i) {
        if (idx + i < NNODE) rp[r * (NNODE + 1) + idx + i] = run;
        run += v[i];
    }
    if (tid == 255) bsum[r * 128 + blockIdx.x] = sm[255];
}

__global__ void scan_phase2(int* __restrict__ bsum) {
    int r = blockIdx.y;
    int tid = threadIdx.x;  // 128 threads
    int v = (tid < NB) ? bsum[r * 128 + tid] : 0;
    __shared__ int sm[128];
    sm[tid] = v;
    __syncthreads();
    for (int off = 1; off < 128; off <<= 1) {
        int t = 0;
        if (tid >= off) t = sm[tid - off];
        __syncthreads();
        sm[tid] += t;
        __syncthreads();
    }
    if (tid < NB) bsum[r * 128 + tid] = sm[tid] - v;
}

__global__ void scan_phase3(int* __restrict__ rp, const int* __restrict__ bsum,
                            int* __restrict__ cursor) {
    int r = blockIdx.y;
    int tid = threadIdx.x;
    int off = bsum[r * 128 + blockIdx.x];
    int idx = blockIdx.x * SCAN_TILE + tid * 4;
#pragma unroll
    for (int i = 0; i < 4; ++i) {
        int ii = idx + i;
        if (ii < NNODE) {
            int val = rp[r * (NNODE + 1) + ii] + off;
            rp[r * (NNODE + 1) + ii] = val;
            cursor[r * NNODE + ii] = val;
        }
    }
    if (blockIdx.x == 0 && tid == 0) rp[r * (NNODE + 1) + NNODE] = NEDGE;
}

// scatter edges into CSR (sorted by dst); col[pos] = src
__global__ void scatter_kernel(const int* __restrict__ sb, const int* __restrict__ db,
                               const int* __restrict__ sr, const int* __restrict__ dr,
                               const int* __restrict__ sj, const int* __restrict__ dj,
                               int* __restrict__ cursor, int* __restrict__ col) {
    int r = blockIdx.y;
    int e = blockIdx.x * blockDim.x + threadIdx.x;
    if (e >= NEDGE) return;
    const int* s = (r == 0) ? sb : (r == 1) ? sr : sj;
    const int* d = (r == 0) ? db : (r == 1) ? dr : dj;
    int pos = atomicAdd(&cursor[r * NNODE + d[e]], 1);
    col[r * NEDGE + pos] = s[e];
}

__global__ void bias_sums(const float* __restrict__ b1b, const float* __restrict__ b1r,
                          const float* __restrict__ b1j, const float* __restrict__ b2b,
                          const float* __restrict__ b2r, const float* __restrict__ b2j,
                          float* __restrict__ b1s, float* __restrict__ b2s) {
    int i = threadIdx.x;  // 256 threads
    if (i < FHID) b1s[i] = b1b[i] + b1r[i] + b1j[i];
    if (i < FOUT) b2s[i] = b2b[i] + b2r[i] + b2j[i];
}

// --------------------------------------------------------------- SpMM (CSR)
// one wave per dst node; lane covers 2 floats (64 lanes x 2 = 128 feats)
// single relation per launch: rp/col/c_src/c_dst already offset by caller.

__global__ __launch_bounds__(256)
void spmm1_kernel(const float2* __restrict__ x2, const int* __restrict__ rp,
                  const int* __restrict__ col, const float* __restrict__ c_src,
                  const float* __restrict__ c_dst, float2* __restrict__ agg2) {
    int wid = (blockIdx.x * blockDim.x + threadIdx.x) >> 6;  // node id
    int lane = threadIdx.x & 63;
    if (wid >= NNODE) return;
    int e0 = rp[wid];
    int e1 = rp[wid + 1];
    float ax = 0.f, ay = 0.f;
    for (int e = e0; e < e1; ++e) {
        int s = col[e];
        float w = c_src[s];
        float2 xv = x2[(size_t)s * (FIN / 2) + lane];
        ax += w * xv.x;
        ay += w * xv.y;
    }
    float cd = c_dst[wid];
    float2 o;
    o.x = ax * cd;
    o.y = ay * cd;
    agg2[(size_t)wid * (FIN / 2) + lane] = o;  // [N][128]
}

// layer 2: gather y rows, accumulate into out. INIT=1: start from bias sum.
template <int INIT>
__global__ __launch_bounds__(256)
void spmm2_kernel(const float2* __restrict__ y2, const int* __restrict__ rp,
                  const int* __restrict__ col, const float* __restrict__ c_src,
                  const float* __restrict__ c_dst, const float2* __restrict__ b2s2,
                  float2* __restrict__ out2) {
    int wid = (blockIdx.x * blockDim.x + threadIdx.x) >> 6;
    int lane = threadIdx.x & 63;
    if (wid >= NNODE) return;
    float2 acc;
    if (INIT) acc = b2s2[lane];
    else      acc = out2[(size_t)wid * (FOUT / 2) + lane];
    int e0 = rp[wid];
    int e1 = rp[wid + 1];
    float ax = 0.f, ay = 0.f;
    for (int e = e0; e < e1; ++e) {
        int s = col[e];
        float w = c_src[s];
        float2 yv = y2[(size_t)s * (FOUT / 2) + lane];
        ax += w * yv.x;
        ay += w * yv.y;
    }
    float cd = c_dst[wid];
    acc.x += cd * ax;
    acc.y += cd * ay;
    out2[(size_t)wid * (FOUT / 2) + lane] = acc;
}

// ------------------------------------------------------------ fp32 GEMM
// C[M][ldc] = op(A[M][K]) * B[K][ldc] (+bias) (+= if ACCUM). op = ReLU if RELUA.
// 128x128 tile, 8x8 per thread, 256 threads.

template <int ACCUM, int RELUA, int HASBIAS>
__global__ __launch_bounds__(256)
void gemm_kernel(const float* __restrict__ A, const float* __restrict__ B,
                 const float* __restrict__ bias, float* __restrict__ C,
                 int M, int K, int ldc) {
    __shared__ float As[16][132];  // transposed: As[k][m]
    __shared__ float Bs[16][132];  // Bs[k][n]
    const int bm = blockIdx.x * 128;
    const int bn = blockIdx.y * 128;
    const int tid = threadIdx.x;
    const int tn = tid & 15;
    const int tm = tid >> 4;
    float acc[8][8] = {};

    for (int k0 = 0; k0 < K; k0 += 16) {
        {   // load A tile 128x16, store transposed
            int row = tid >> 2;
            int kq = (tid & 3) * 4;
#pragma unroll
            for (int h = 0; h < 2; ++h) {
                int rr = row + h * 64;
                int ar = bm + rr;
                float4 v = make_float4(0.f, 0.f, 0.f, 0.f);
                if (ar < M) v = *(const float4*)&A[(size_t)ar * K + k0 + kq];
                if (RELUA) {
                    v.x = fmaxf(v.x, 0.f);
                    v.y = fmaxf(v.y, 0.f);
                    v.z = fmaxf(v.z, 0.f);
                    v.w = fmaxf(v.w, 0.f);
                }
                As[kq + 0][rr] = v.x;
                As[kq + 1][rr] = v.y;
                As[kq + 2][rr] = v.z;
                As[kq + 3][rr] = v.w;
            }
            // load B tile 16x128 (col dims always divisible by 128)
            int brow = tid >> 5;
            int bc = (tid & 31) * 4;
#pragma unroll
            for (int h = 0; h < 2; ++h) {
                int r2 = brow + h * 8;
                float4 v = *(const float4*)&B[(size_t)(k0 + r2) * ldc + bn + bc];
                *(float4*)&Bs[r2][bc] = v;
            }
        }
        __syncthreads();
#pragma unroll
        for (int k = 0; k < 16; ++k) {
            float4 a0 = *(float4*)&As[k][tm * 8];
            float4 a1 = *(float4*)&As[k][tm * 8 + 4];
            float4 b0 = *(float4*)&Bs[k][tn * 8];
            float4 b1 = *(float4*)&Bs[k][tn * 8 + 4];
            float a[8] = {a0.x, a0.y, a0.z, a0.w, a1.x, a1.y, a1.z, a1.w};
            float b[8] = {b0.x, b0.y, b0.z, b0.w, b1.x, b1.y, b1.z, b1.w};
#pragma unroll
            for (int i = 0; i < 8; ++i)
#pragma unroll
                for (int j = 0; j < 8; ++j) acc[i][j] += a[i] * b[j];
        }
        __syncthreads();
    }

#pragma unroll
    for (int i = 0; i < 8; ++i) {
        int row = bm + tm * 8 + i;
        if (row < M) {
#pragma unroll
            for (int jv = 0; jv < 2; ++jv) {
                int colb = bn + tn * 8 + jv * 4;
                float4 v = make_float4(acc[i][jv * 4 + 0], acc[i][jv * 4 + 1],
                                       acc[i][jv * 4 + 2], acc[i][jv * 4 + 3]);
                float* cp = &C[(size_t)row * ldc + colb];
                if (HASBIAS) {
                    v.x += bias[colb + 0];
                    v.y += bias[colb + 1];
                    v.z += bias[colb + 2];
                    v.w += bias[colb + 3];
                }
                if (ACCUM) {
                    float4 o = *(float4*)cp;
                    v.x += o.x;
                    v.y += o.y;
                    v.z += o.z;
                    v.w += o.w;
                }
                *(float4*)cp = v;
            }
        }
    }
}

// ---------------------------------------------------------------- launcher

extern "C" void kernel_launch(void* const* d_in, const int* in_sizes, int n_in,
                              void* d_out, int out_size, void* d_ws, size_t ws_size,
                              hipStream_t stream) {
    // setup_inputs() dict order:
    const float* x = (const float*)d_in[0];
    const int* src_b = (const int*)d_in[1];
    const int* dst_b = (const int*)d_in[2];
    const int* src_r = (const int*)d_in[3];
    const int* dst_r = (const int*)d_in[4];
    const int* src_j = (const int*)d_in[5];
    const int* dst_j = (const int*)d_in[6];
    const float* W1[3] = {(const float*)d_in[7], (const float*)d_in[11], (const float*)d_in[15]};
    const float* b1[3] = {(const float*)d_in[8], (const float*)d_in[12], (const float*)d_in[16]};
    const float* W2[3] = {(const float*)d_in[9], (const float*)d_in[13], (const float*)d_in[17]};
    const float* b2[3] = {(const float*)d_in[10], (const float*)d_in[14], (const float*)d_in[18]};
    float* out = (float*)d_out;

    char* w = (char*)d_ws;
    auto alloc = [&](size_t bytes) -> char* {
        char* p = w;
        w += (bytes + 255) & ~(size_t)255;
        return p;
    };
    // total ~167 MB (was ~270 MB — suspected d_ws overflow caused the fault)
    int* cnt = (int*)alloc((size_t)6 * NNODE * 4);  // cnt_src[3N] | cnt_dst[3N]
    int* cnt_src = cnt;
    int* cnt_dst = cnt + 3 * NNODE;
    float* c_src = (float*)alloc((size_t)3 * NNODE * 4);
    float* c_dst = (float*)alloc((size_t)3 * NNODE * 4);
    int* rp = (int*)alloc((size_t)3 * (NNODE + 1) * 4);
    int* bsum = (int*)alloc((size_t)3 * 128 * 4);
    int* cursor = (int*)alloc((size_t)3 * NNODE * 4);
    int* col = (int*)alloc((size_t)3 * NEDGE * 4);
    float* b1s = (float*)alloc(FHID * 4);
    float* b2s = (float*)alloc(FOUT * 4);
    float* aggy = (float*)alloc((size_t)NNODE * FIN * 4);  // [N][128] agg (L1) / y (L2)
    float* h = (float*)alloc((size_t)NNODE * FHID * 4);    // [N][256]

    const int T = 256;

    // 1. graph preprocessing
    zero_ints<<<dim3((6 * NNODE + T - 1) / T), T, 0, stream>>>(cnt, 6 * NNODE);
    degrees_kernel<<<dim3((NEDGE + T - 1) / T, 3), T, 0, stream>>>(
        src_b, dst_b, src_r, dst_r, src_j, dst_j, cnt_src, cnt_dst);
    norms_kernel<<<dim3((3 * NNODE + T - 1) / T), T, 0, stream>>>(cnt_src, cnt_dst, c_src, c_dst);
    scan_phase1<<<dim3(NB, 3), 256, 0, stream>>>(cnt_dst, rp, bsum);
    scan_phase2<<<dim3(1, 3), 128, 0, stream>>>(bsum);
    scan_phase3<<<dim3(NB, 3), 256, 0, stream>>>(rp, bsum, cursor);
    scatter_kernel<<<dim3((NEDGE + T - 1) / T, 3), T, 0, stream>>>(
        src_b, dst_b, src_r, dst_r, src_j, dst_j, cursor, col);
    bias_sums<<<1, 256, 0, stream>>>(b1[0], b1[1], b1[2], b2[0], b2[1], b2[2], b1s, b2s);

    const dim3 spmm_grid((NNODE * 64 + T - 1) / T);
    const dim3 gemm1_grid((NNODE + 127) / 128, FHID / 128);
    const dim3 gemm2_grid((NNODE + 127) / 128, FOUT / 128);

    // 3. layer 1: per relation, aggregate -> aggbuf [N,128], GEMM accumulate h [N,256]
    for (int r = 0; r < 3; ++r) {
        spmm1_kernel<<<spmm_grid, T, 0, stream>>>(
            (const float2*)x, rp + r * (NNODE + 1), col + (size_t)r * NEDGE,
            c_src + r * NNODE, c_dst + r * NNODE, (float2*)aggy);
        if (r == 0)
            gemm_kernel<0, 0, 1><<<gemm1_grid, 256, 0, stream>>>(
                aggy, W1[r], b1s, h, NNODE, FIN, FHID);
        else
            gemm_kernel<1, 0, 0><<<gemm1_grid, 256, 0, stream>>>(
                aggy, W1[r], nullptr, h, NNODE, FIN, FHID);
    }

    // 4. layer 2: per relation, y = relu(h) @ W2_r, then SpMM accumulate into out
    for (int r = 0; r < 3; ++r) {
        gemm_kernel<0, 1, 0><<<gemm2_grid, 256, 0, stream>>>(
            h, W2[r], nullptr, aggy, NNODE, FHID, FOUT);
        if (r == 0)
            spmm2_kernel<1><<<spmm_grid, T, 0, stream>>>(
                (const float2*)aggy, rp + r * (NNODE + 1), col + (size_t)r * NEDGE,
                c_src + r * NNODE, c_dst + r * NNODE, (const float2*)b2s, (float2*)out);
        else
            spmm2_kernel<0><<<spmm_grid, T, 0, stream>>>(
                (const float2*)aggy, rp + r * (NNODE + 1), col + (size_t)r * NEDGE,
                c_src + r * NNODE, c_dst + r * NNODE, (const float2*)b2s, (float2*)out);
    }
}

// Round 3
// 1141.516 us; speedup vs baseline: 1.2283x; 1.2283x over previous
//
#include <hip/hip_runtime.h>
#include <hip/hip_bf16.h>
#include <cstdint>

#define NNODE 100000
#define NEDGE 500000
#define FIN   128
#define FHID  256
#define FOUT  128

typedef __attribute__((ext_vector_type(8))) short bf16x8;
typedef __attribute__((ext_vector_type(4))) float f32x4;

// ---------------------------------------------------------------- bf16 split

__device__ inline unsigned short f2bf(float f) {
    unsigned int u = __float_as_uint(f);
    unsigned int r = (u + 0x7FFF + ((u >> 16) & 1)) >> 16;
    return (unsigned short)r;
}
__device__ inline float bf2f(unsigned short s) {
    return __uint_as_float(((unsigned int)s) << 16);
}
__device__ inline void split2(float f, unsigned short& hi, unsigned short& lo) {
    hi = f2bf(f);
    lo = f2bf(f - bf2f(hi));
}

// ---------------------------------------------------------------- utilities

__global__ void zero_ints(int* __restrict__ p, int n) {
    int i = blockIdx.x * blockDim.x + threadIdx.x;
    if (i < n) p[i] = 0;
}

__global__ void degrees_kernel(const int* __restrict__ sb, const int* __restrict__ db,
                               const int* __restrict__ sr, const int* __restrict__ dr,
                               const int* __restrict__ sj, const int* __restrict__ dj,
                               int* __restrict__ cnt_src, int* __restrict__ cnt_dst) {
    int r = blockIdx.y;
    int e = blockIdx.x * blockDim.x + threadIdx.x;
    if (e >= NEDGE) return;
    const int* s = (r == 0) ? sb : (r == 1) ? sr : sj;
    const int* d = (r == 0) ? db : (r == 1) ? dr : dj;
    atomicAdd(&cnt_src[r * NNODE + s[e]], 1);
    atomicAdd(&cnt_dst[r * NNODE + d[e]], 1);
}

__global__ void norms_kernel(const int* __restrict__ cnt_src, const int* __restrict__ cnt_dst,
                             float* __restrict__ c_src, float* __restrict__ c_dst) {
    int i = blockIdx.x * blockDim.x + threadIdx.x;
    if (i >= 3 * NNODE) return;
    c_src[i] = rsqrtf((float)max(cnt_src[i], 1));
    c_dst[i] = rsqrtf((float)max(cnt_dst[i], 1));
}

#define SCAN_TILE 1024
#define NB 98   // ceil(100000/1024)

__global__ void scan_phase1(const int* __restrict__ cnt_dst, int* __restrict__ rp,
                            int* __restrict__ bsum) {
    int r = blockIdx.y;
    int tid = threadIdx.x;
    int idx = blockIdx.x * SCAN_TILE + tid * 4;
    int v[4];
#pragma unroll
    for (int i = 0; i < 4; ++i)
        v[i] = (idx + i < NNODE) ? cnt_dst[r * NNODE + idx + i] : 0;
    int tsum = v[0] + v[1] + v[2] + v[3];
    __shared__ int sm[256];
    sm[tid] = tsum;
    __syncthreads();
    for (int off = 1; off < 256; off <<= 1) {
        int t = 0;
        if (tid >= off) t = sm[tid - off];
        __syncthreads();
        sm[tid] += t;
        __syncthreads();
    }
    int excl = sm[tid] - tsum;
    int run = excl;
#pragma unroll
    for (int i = 0; i < 4; ++i) {
        if (idx + i < NNODE) rp[r * (NNODE + 1) + idx + i] = run;
        run += v[i];
    }
    if (tid == 255) bsum[r * 128 + blockIdx.x] = sm[255];
}

__global__ void scan_phase2(int* __restrict__ bsum) {
    int r = blockIdx.y;
    int tid = threadIdx.x;  // 128 threads
    int v = (tid < NB) ? bsum[r * 128 + tid] : 0;
    __shared__ int sm[128];
    sm[tid] = v;
    __syncthreads();
    for (int off = 1; off < 128; off <<= 1) {
        int t = 0;
        if (tid >= off) t = sm[tid - off];
        __syncthreads();
        sm[tid] += t;
        __syncthreads();
    }
    if (tid < NB) bsum[r * 128 + tid] = sm[tid] - v;
}

__global__ void scan_phase3(int* __restrict__ rp, const int* __restrict__ bsum,
                            int* __restrict__ cursor) {
    int r = blockIdx.y;
    int tid = threadIdx.x;
    int off = bsum[r * 128 + blockIdx.x];
    int idx = blockIdx.x * SCAN_TILE + tid * 4;
#pragma unroll
    for (int i = 0; i < 4; ++i) {
        int ii = idx + i;
        if (ii < NNODE) {
            int val = rp[r * (NNODE + 1) + ii] + off;
            rp[r * (NNODE + 1) + ii] = val;
            cursor[r * NNODE + ii] = val;
        }
    }
    if (blockIdx.x == 0 && tid == 0) rp[r * (NNODE + 1) + NNODE] = NEDGE;
}

__global__ void scatter_kernel(const int* __restrict__ sb, const int* __restrict__ db,
                               const int* __restrict__ sr, const int* __restrict__ dr,
                               const int* __restrict__ sj, const int* __restrict__ dj,
                               int* __restrict__ cursor, int* __restrict__ col) {
    int r = blockIdx.y;
    int e = blockIdx.x * blockDim.x + threadIdx.x;
    if (e >= NEDGE) return;
    const int* s = (r == 0) ? sb : (r == 1) ? sr : sj;
    const int* d = (r == 0) ? db : (r == 1) ? dr : dj;
    int pos = atomicAdd(&cursor[r * NNODE + d[e]], 1);
    col[r * NEDGE + pos] = s[e];
}

__global__ void bias_sums(const float* __restrict__ b1b, const float* __restrict__ b1r,
                          const float* __restrict__ b1j, const float* __restrict__ b2b,
                          const float* __restrict__ b2r, const float* __restrict__ b2j,
                          float* __restrict__ b1s, float* __restrict__ b2s) {
    int i = threadIdx.x;  // 256 threads
    if (i < FHID) b1s[i] = b1b[i] + b1r[i] + b1j[i];
    if (i < FOUT) b2s[i] = b2b[i] + b2r[i] + b2j[i];
}

// W [K][N] fp32 -> Wt_hi/lo [N][K] bf16 (transpose + split)
__global__ void wsplit_kernel(const float* __restrict__ W, unsigned short* __restrict__ th,
                              unsigned short* __restrict__ tl, int K, int N) {
    int i = blockIdx.x * blockDim.x + threadIdx.x;
    if (i >= K * N) return;
    int k = i / N;
    int n = i - k * N;
    unsigned short hi, lo;
    split2(W[i], hi, lo);
    th[n * K + k] = hi;
    tl[n * K + k] = lo;
}

// --------------------------------------------------------------- SpMM (CSR)
// one wave per dst node; lane covers 2 floats. Emits bf16 hi/lo planes.

__global__ __launch_bounds__(256)
void spmm1_kernel(const float2* __restrict__ x2, const int* __restrict__ rp,
                  const int* __restrict__ col, const float* __restrict__ c_src,
                  const float* __restrict__ c_dst, ushort2* __restrict__ agg_h,
                  ushort2* __restrict__ agg_l) {
    int wid = (blockIdx.x * blockDim.x + threadIdx.x) >> 6;  // node id
    int lane = threadIdx.x & 63;
    if (wid >= NNODE) return;
    int e0 = rp[wid];
    int e1 = rp[wid + 1];
    float ax = 0.f, ay = 0.f;
    for (int e = e0; e < e1; ++e) {
        int s = col[e];
        float w = c_src[s];
        float2 xv = x2[(size_t)s * (FIN / 2) + lane];
        ax += w * xv.x;
        ay += w * xv.y;
    }
    float cd = c_dst[wid];
    ax *= cd;
    ay *= cd;
    unsigned short hx, lx, hy, ly;
    split2(ax, hx, lx);
    split2(ay, hy, ly);
    size_t o = (size_t)wid * (FIN / 2) + lane;
    agg_h[o] = ushort2{hx, hy};
    agg_l[o] = ushort2{lx, ly};
}

// layer 2: gather y rows, accumulate into out. INIT=1: start from bias sum.
template <int INIT>
__global__ __launch_bounds__(256)
void spmm2_kernel(const float2* __restrict__ y2, const int* __restrict__ rp,
                  const int* __restrict__ col, const float* __restrict__ c_src,
                  const float* __restrict__ c_dst, const float2* __restrict__ b2s2,
                  float2* __restrict__ out2) {
    int wid = (blockIdx.x * blockDim.x + threadIdx.x) >> 6;
    int lane = threadIdx.x & 63;
    if (wid >= NNODE) return;
    float2 acc;
    if (INIT) acc = b2s2[lane];
    else      acc = out2[(size_t)wid * (FOUT / 2) + lane];
    int e0 = rp[wid];
    int e1 = rp[wid + 1];
    float ax = 0.f, ay = 0.f;
    for (int e = e0; e < e1; ++e) {
        int s = col[e];
        float w = c_src[s];
        float2 yv = y2[(size_t)s * (FOUT / 2) + lane];
        ax += w * yv.x;
        ay += w * yv.y;
    }
    float cd = c_dst[wid];
    acc.x += cd * ax;
    acc.y += cd * ay;
    out2[(size_t)wid * (FOUT / 2) + lane] = acc;
}

// ------------------------------------------------------------ MFMA GEMM
// C[M][N] = A[M][K] @ B[K][N], A given as hi/lo bf16 planes [M][K],
// B given pre-transposed as hi/lo bf16 planes [N][K].
// 2-term split: acc += Ah*Bh + Ah*Bl + Al*Bh   (fp32 MFMA accumulation)
// 128x128 tile, BK=32, 4 waves (2x2), each wave 64x64 via 4x4 frags 16x16x32.
// EPI: 0 = store h=acc+bias (split planes); 1 = h += acc; 2 = h = relu(h+acc);
//      3 = store fp32.

template <int K, int EPI>
__global__ __launch_bounds__(256)
void gemm_mfma(const unsigned short* __restrict__ Ah, const unsigned short* __restrict__ Al,
               const unsigned short* __restrict__ Bh, const unsigned short* __restrict__ Bl,
               const float* __restrict__ bias, unsigned short* __restrict__ Ch,
               unsigned short* __restrict__ Cl, float* __restrict__ Cf, int M, int N) {
    __shared__ unsigned short As_h[128][40], As_l[128][40];
    __shared__ unsigned short Bs_h[128][40], Bs_l[128][40];
    const int bm = blockIdx.x * 128;
    const int bn = blockIdx.y * 128;
    const int tid = threadIdx.x;
    const int lane = tid & 63;
    const int wv = tid >> 6;
    const int wm = (wv >> 1) * 64;
    const int wn = (wv & 1) * 64;

    const int srow = tid >> 1;          // 0..127
    const int scol = (tid & 1) * 16;    // shorts
    const size_t abase = (size_t)(bm + srow) * K + scol;
    const size_t bbase = (size_t)(bn + srow) * K + scol;
    const bool avalid = (bm + srow) < M;

    f32x4 acc[4][4] = {};

    for (int k0 = 0; k0 < K; k0 += 32) {
        uint4 z = make_uint4(0, 0, 0, 0);
        uint4 a0 = z, a1 = z, l0 = z, l1 = z;
        if (avalid) {
            a0 = *(const uint4*)&Ah[abase + k0];
            a1 = *(const uint4*)&Ah[abase + k0 + 8];
            l0 = *(const uint4*)&Al[abase + k0];
            l1 = *(const uint4*)&Al[abase + k0 + 8];
        }
        uint4 b0 = *(const uint4*)&Bh[bbase + k0];
        uint4 b1 = *(const uint4*)&Bh[bbase + k0 + 8];
        uint4 m0 = *(const uint4*)&Bl[bbase + k0];
        uint4 m1 = *(const uint4*)&Bl[bbase + k0 + 8];
        *(uint4*)&As_h[srow][scol] = a0;
        *(uint4*)&As_h[srow][scol + 8] = a1;
        *(uint4*)&As_l[srow][scol] = l0;
        *(uint4*)&As_l[srow][scol + 8] = l1;
        *(uint4*)&Bs_h[srow][scol] = b0;
        *(uint4*)&Bs_h[srow][scol + 8] = b1;
        *(uint4*)&Bs_l[srow][scol] = m0;
        *(uint4*)&Bs_l[srow][scol + 8] = m1;
        __syncthreads();

        const int kb = (lane >> 4) * 8;
        const int fr = lane & 15;
        bf16x8 ah[4], al[4], bh[4], bl[4];
#pragma unroll
        for (int i = 0; i < 4; ++i) {
            ah[i] = *(const bf16x8*)&As_h[wm + i * 16 + fr][kb];
            al[i] = *(const bf16x8*)&As_l[wm + i * 16 + fr][kb];
            bh[i] = *(const bf16x8*)&Bs_h[wn + i * 16 + fr][kb];
            bl[i] = *(const bf16x8*)&Bs_l[wn + i * 16 + fr][kb];
        }
#pragma unroll
        for (int mi = 0; mi < 4; ++mi)
#pragma unroll
            for (int ni = 0; ni < 4; ++ni) {
                acc[mi][ni] = __builtin_amdgcn_mfma_f32_16x16x32_bf16(ah[mi], bh[ni], acc[mi][ni], 0, 0, 0);
                acc[mi][ni] = __builtin_amdgcn_mfma_f32_16x16x32_bf16(ah[mi], bl[ni], acc[mi][ni], 0, 0, 0);
                acc[mi][ni] = __builtin_amdgcn_mfma_f32_16x16x32_bf16(al[mi], bh[ni], acc[mi][ni], 0, 0, 0);
            }
        __syncthreads();
    }

    // epilogue: C/D map col=lane&15, row=(lane>>4)*4+reg
    const int cl = lane & 15;
    const int rl = (lane >> 4) * 4;
#pragma unroll
    for (int mi = 0; mi < 4; ++mi) {
#pragma unroll
        for (int ni = 0; ni < 4; ++ni) {
            const int gcol = bn + wn + ni * 16 + cl;
#pragma unroll
            for (int rg = 0; rg < 4; ++rg) {
                const int grow = bm + wm + mi * 16 + rl + rg;
                if (grow < M) {
                    float v = acc[mi][ni][rg];
                    const size_t idx = (size_t)grow * N + gcol;
                    if (EPI == 0) {
                        v += bias[gcol];
                        unsigned short hi, lo;
                        split2(v, hi, lo);
                        Ch[idx] = hi;
                        Cl[idx] = lo;
                    } else if (EPI == 1 || EPI == 2) {
                        v += bf2f(Ch[idx]) + bf2f(Cl[idx]);
                        if (EPI == 2) v = fmaxf(v, 0.f);
                        unsigned short hi, lo;
                        split2(v, hi, lo);
                        Ch[idx] = hi;
                        Cl[idx] = lo;
                    } else {
                        Cf[idx] = v;
                    }
                }
            }
        }
    }
}

// ---------------------------------------------------------------- launcher

extern "C" void kernel_launch(void* const* d_in, const int* in_sizes, int n_in,
                              void* d_out, int out_size, void* d_ws, size_t ws_size,
                              hipStream_t stream) {
    const float* x = (const float*)d_in[0];
    const int* src_b = (const int*)d_in[1];
    const int* dst_b = (const int*)d_in[2];
    const int* src_r = (const int*)d_in[3];
    const int* dst_r = (const int*)d_in[4];
    const int* src_j = (const int*)d_in[5];
    const int* dst_j = (const int*)d_in[6];
    const float* W1[3] = {(const float*)d_in[7], (const float*)d_in[11], (const float*)d_in[15]};
    const float* b1[3] = {(const float*)d_in[8], (const float*)d_in[12], (const float*)d_in[16]};
    const float* W2[3] = {(const float*)d_in[9], (const float*)d_in[13], (const float*)d_in[17]};
    const float* b2[3] = {(const float*)d_in[10], (const float*)d_in[14], (const float*)d_in[18]};
    float* out = (float*)d_out;

    char* w = (char*)d_ws;
    auto alloc = [&](size_t bytes) -> char* {
        char* p = w;
        w += (bytes + 255) & ~(size_t)255;
        return p;
    };
    // ~167 MB total (same proven footprint as round 2)
    int* cnt = (int*)alloc((size_t)6 * NNODE * 4);  // cnt_src[3N] | cnt_dst[3N]
    int* cnt_src = cnt;
    int* cnt_dst = cnt + 3 * NNODE;
    float* c_src = (float*)alloc((size_t)3 * NNODE * 4);
    float* c_dst = (float*)alloc((size_t)3 * NNODE * 4);
    int* rp = (int*)alloc((size_t)3 * (NNODE + 1) * 4);
    int* bsum = (int*)alloc((size_t)3 * 128 * 4);
    int* cursor = (int*)alloc((size_t)3 * NNODE * 4);
    int* col = (int*)alloc((size_t)3 * NEDGE * 4);
    float* b1s = (float*)alloc(FHID * 4);
    float* b2s = (float*)alloc(FOUT * 4);
    char* abuf = alloc((size_t)NNODE * FIN * 4);        // agg hi/lo planes OR y fp32
    unsigned short* agg_h = (unsigned short*)abuf;      // [N][128] bf16
    unsigned short* agg_l = agg_h + (size_t)NNODE * FIN;
    float* yb = (float*)abuf;                           // [N][128] fp32 (layer 2)
    char* hbuf = alloc((size_t)NNODE * FHID * 4);       // h hi/lo planes
    unsigned short* h_h = (unsigned short*)hbuf;        // [N][256] bf16
    unsigned short* h_l = h_h + (size_t)NNODE * FHID;

    // weight planes aliased over cnt (dead after scan_phase1); 786 KB < 2.4 MB
    unsigned short* w1h = (unsigned short*)cnt;
    unsigned short* w1l = w1h + 3 * FIN * FHID;
    unsigned short* w2h = w1l + 3 * FIN * FHID;
    unsigned short* w2l = w2h + 3 * FHID * FOUT;

    const int T = 256;

    // 1. graph preprocessing
    zero_ints<<<dim3((6 * NNODE + T - 1) / T), T, 0, stream>>>(cnt, 6 * NNODE);
    degrees_kernel<<<dim3((NEDGE + T - 1) / T, 3), T, 0, stream>>>(
        src_b, dst_b, src_r, dst_r, src_j, dst_j, cnt_src, cnt_dst);
    norms_kernel<<<dim3((3 * NNODE + T - 1) / T), T, 0, stream>>>(cnt_src, cnt_dst, c_src, c_dst);
    scan_phase1<<<dim3(NB, 3), 256, 0, stream>>>(cnt_dst, rp, bsum);
    scan_phase2<<<dim3(1, 3), 128, 0, stream>>>(bsum);
    scan_phase3<<<dim3(NB, 3), 256, 0, stream>>>(rp, bsum, cursor);
    scatter_kernel<<<dim3((NEDGE + T - 1) / T, 3), T, 0, stream>>>(
        src_b, dst_b, src_r, dst_r, src_j, dst_j, cursor, col);

    // 2. weight prep (cnt region now dead -> safe to overwrite)
    for (int r = 0; r < 3; ++r) {
        wsplit_kernel<<<dim3((FIN * FHID + T - 1) / T), T, 0, stream>>>(
            W1[r], w1h + r * FIN * FHID, w1l + r * FIN * FHID, FIN, FHID);
        wsplit_kernel<<<dim3((FHID * FOUT + T - 1) / T), T, 0, stream>>>(
            W2[r], w2h + r * FHID * FOUT, w2l + r * FHID * FOUT, FHID, FOUT);
    }
    bias_sums<<<1, 256, 0, stream>>>(b1[0], b1[1], b1[2], b2[0], b2[1], b2[2], b1s, b2s);

    const dim3 spmm_grid((NNODE * 64 + T - 1) / T);
    const dim3 g1grid((NNODE + 127) / 128, FHID / 128);
    const dim3 g2grid((NNODE + 127) / 128, FOUT / 128);

    // 3. layer 1: per relation, aggregate -> bf16 planes, MFMA GEMM accumulate h
    for (int r = 0; r < 3; ++r) {
        spmm1_kernel<<<spmm_grid, T, 0, stream>>>(
            (const float2*)x, rp + r * (NNODE + 1), col + (size_t)r * NEDGE,
            c_src + r * NNODE, c_dst + r * NNODE, (ushort2*)agg_h, (ushort2*)agg_l);
        if (r == 0)
            gemm_mfma<FIN, 0><<<g1grid, 256, 0, stream>>>(
                agg_h, agg_l, w1h, w1l, b1s, h_h, h_l, nullptr, NNODE, FHID);
        else if (r == 1)
            gemm_mfma<FIN, 1><<<g1grid, 256, 0, stream>>>(
                agg_h, agg_l, w1h + FIN * FHID, w1l + FIN * FHID, nullptr,
                h_h, h_l, nullptr, NNODE, FHID);
        else
            gemm_mfma<FIN, 2><<<g1grid, 256, 0, stream>>>(
                agg_h, agg_l, w1h + 2 * FIN * FHID, w1l + 2 * FIN * FHID, nullptr,
                h_h, h_l, nullptr, NNODE, FHID);  // + relu
    }

    // 4. layer 2: per relation, y = h @ W2_r (MFMA) -> fp32, SpMM accumulate out
    for (int r = 0; r < 3; ++r) {
        gemm_mfma<FHID, 3><<<g2grid, 256, 0, stream>>>(
            h_h, h_l, w2h + r * FHID * FOUT, w2l + r * FHID * FOUT, nullptr,
            nullptr, nullptr, yb, NNODE, FOUT);
        if (r == 0)
            spmm2_kernel<1><<<spmm_grid, T, 0, stream>>>(
                (const float2*)yb, rp + r * (NNODE + 1), col + (size_t)r * NEDGE,
                c_src + r * NNODE, c_dst + r * NNODE, (const float2*)b2s, (float2*)out);
        else
            spmm2_kernel<0><<<spmm_grid, T, 0, stream>>>(
                (const float2*)yb, rp + r * (NNODE + 1), col + (size_t)r * NEDGE,
                c_src + r * NNODE, c_dst + r * NNODE, (const float2*)b2s, (float2*)out);
    }
}

// Round 4
// 773.960 us; speedup vs baseline: 1.8116x; 1.4749x over previous
//
#include <hip/hip_runtime.h>
#include <hip/hip_bf16.h>
#include <cstdint>

#define NNODE 100000
#define NEDGE 500000
#define FIN   128
#define FHID  256
#define FOUT  128

typedef __attribute__((ext_vector_type(8))) short bf16x8;
typedef __attribute__((ext_vector_type(4))) float f32x4;

// ---------------------------------------------------------------- bf16 utils

__device__ inline unsigned short f2bf(float f) {
    unsigned int u = __float_as_uint(f);
    unsigned int r = (u + 0x7FFF + ((u >> 16) & 1)) >> 16;
    return (unsigned short)r;
}
__device__ inline float bf2f(unsigned short s) {
    return __uint_as_float(((unsigned int)s) << 16);
}
__device__ inline void split2(float f, unsigned short& hi, unsigned short& lo) {
    hi = f2bf(f);
    lo = f2bf(f - bf2f(hi));
}

// ---------------------------------------------------------------- utilities

__global__ void zero_ints(int* __restrict__ p, int n) {
    int i = blockIdx.x * blockDim.x + threadIdx.x;
    if (i < n) p[i] = 0;
}

// degrees + per-edge rank (rank = old count at dst — enables atomic-free scatter)
__global__ void degrees_kernel(const int* __restrict__ sb, const int* __restrict__ db,
                               const int* __restrict__ sr, const int* __restrict__ dr,
                               const int* __restrict__ sj, const int* __restrict__ dj,
                               int* __restrict__ cnt_src, int* __restrict__ cnt_dst,
                               int* __restrict__ rank) {
    int r = blockIdx.y;
    int e = blockIdx.x * blockDim.x + threadIdx.x;
    if (e >= NEDGE) return;
    const int* s = (r == 0) ? sb : (r == 1) ? sr : sj;
    const int* d = (r == 0) ? db : (r == 1) ? dr : dj;
    atomicAdd(&cnt_src[r * NNODE + s[e]], 1);
    rank[r * NEDGE + e] = atomicAdd(&cnt_dst[r * NNODE + d[e]], 1);
}

__global__ void norms_kernel(const int* __restrict__ cnt_src, const int* __restrict__ cnt_dst,
                             float* __restrict__ c_src, float* __restrict__ c_dst) {
    int i = blockIdx.x * blockDim.x + threadIdx.x;
    if (i >= 3 * NNODE) return;
    c_src[i] = rsqrtf((float)max(cnt_src[i], 1));
    c_dst[i] = rsqrtf((float)max(cnt_dst[i], 1));
}

#define SCAN_TILE 1024
#define NB 98   // ceil(100000/1024)

__global__ void scan_phase1(const int* __restrict__ cnt_dst, int* __restrict__ rp,
                            int* __restrict__ bsum) {
    int r = blockIdx.y;
    int tid = threadIdx.x;
    int idx = blockIdx.x * SCAN_TILE + tid * 4;
    int v[4];
#pragma unroll
    for (int i = 0; i < 4; ++i)
        v[i] = (idx + i < NNODE) ? cnt_dst[r * NNODE + idx + i] : 0;
    int tsum = v[0] + v[1] + v[2] + v[3];
    __shared__ int sm[256];
    sm[tid] = tsum;
    __syncthreads();
    for (int off = 1; off < 256; off <<= 1) {
        int t = 0;
        if (tid >= off) t = sm[tid - off];
        __syncthreads();
        sm[tid] += t;
        __syncthreads();
    }
    int excl = sm[tid] - tsum;
    int run = excl;
#pragma unroll
    for (int i = 0; i < 4; ++i) {
        if (idx + i < NNODE) rp[r * (NNODE + 1) + idx + i] = run;
        run += v[i];
    }
    if (tid == 255) bsum[r * 128 + blockIdx.x] = sm[255];
}

__global__ void scan_phase2(int* __restrict__ bsum) {
    int r = blockIdx.y;
    int tid = threadIdx.x;  // 128 threads
    int v = (tid < NB) ? bsum[r * 128 + tid] : 0;
    __shared__ int sm[128];
    sm[tid] = v;
    __syncthreads();
    for (int off = 1; off < 128; off <<= 1) {
        int t = 0;
        if (tid >= off) t = sm[tid - off];
        __syncthreads();
        sm[tid] += t;
        __syncthreads();
    }
    if (tid < NB) bsum[r * 128 + tid] = sm[tid] - v;
}

__global__ void scan_phase3(int* __restrict__ rp, const int* __restrict__ bsum) {
    int r = blockIdx.y;
    int tid = threadIdx.x;
    int off = bsum[r * 128 + blockIdx.x];
    int idx = blockIdx.x * SCAN_TILE + tid * 4;
#pragma unroll
    for (int i = 0; i < 4; ++i) {
        int ii = idx + i;
        if (ii < NNODE) rp[r * (NNODE + 1) + ii] += off;
    }
    if (blockIdx.x == 0 && tid == 0) rp[r * (NNODE + 1) + NNODE] = NEDGE;
}

// atomic-free scatter: col[rp[d] + rank[e]] = s
__global__ void scatter_kernel(const int* __restrict__ sb, const int* __restrict__ db,
                               const int* __restrict__ sr, const int* __restrict__ dr,
                               const int* __restrict__ sj, const int* __restrict__ dj,
                               const int* __restrict__ rank, const int* __restrict__ rp,
                               int* __restrict__ col) {
    int r = blockIdx.y;
    int e = blockIdx.x * blockDim.x + threadIdx.x;
    if (e >= NEDGE) return;
    const int* s = (r == 0) ? sb : (r == 1) ? sr : sj;
    const int* d = (r == 0) ? db : (r == 1) ? dr : dj;
    int pos = rp[r * (NNODE + 1) + d[e]] + rank[r * NEDGE + e];
    col[r * NEDGE + pos] = s[e];
}

__global__ void bias_sums(const float* __restrict__ b1b, const float* __restrict__ b1r,
                          const float* __restrict__ b1j, const float* __restrict__ b2b,
                          const float* __restrict__ b2r, const float* __restrict__ b2j,
                          float* __restrict__ b1s, float* __restrict__ b2s) {
    int i = threadIdx.x;  // 256 threads
    if (i < FHID) b1s[i] = b1b[i] + b1r[i] + b1j[i];
    if (i < FOUT) b2s[i] = b2b[i] + b2r[i] + b2j[i];
}

// x fp32 -> bf16 plane
__global__ void x2bf_kernel(const float4* __restrict__ x4, ushort4* __restrict__ xb4, int n4) {
    int i = blockIdx.x * blockDim.x + threadIdx.x;
    if (i >= n4) return;
    float4 v = x4[i];
    ushort4 o;
    o.x = f2bf(v.x);
    o.y = f2bf(v.y);
    o.z = f2bf(v.z);
    o.w = f2bf(v.w);
    xb4[i] = o;
}

// W [K][N] fp32 -> transposed hi/lo bf16 planes at th/tl[(nbase+n)*ldt + kbase + k]
__global__ void wsplit_t(const float* __restrict__ W, unsigned short* __restrict__ th,
                         unsigned short* __restrict__ tl, int K, int N, int ldt,
                         int nbase, int kbase) {
    int i = blockIdx.x * blockDim.x + threadIdx.x;
    if (i >= K * N) return;
    int k = i / N;
    int n = i - k * N;
    unsigned short hi, lo;
    split2(W[i], hi, lo);
    size_t o = (size_t)(nbase + n) * ldt + kbase + k;
    th[o] = hi;
    tl[o] = lo;
}

// --------------------------------------------------------------- SpMM (CSR)
// one wave per dst node, all 3 relations; lane covers 2 feats (ushort2).

__global__ __launch_bounds__(256)
void spmm1_all(const ushort2* __restrict__ xb, const int* __restrict__ rp,
               const int* __restrict__ col, const float* __restrict__ c_src,
               const float* __restrict__ c_dst, ushort2* __restrict__ agg) {
    int wid = (blockIdx.x * blockDim.x + threadIdx.x) >> 6;
    int lane = threadIdx.x & 63;
    if (wid >= NNODE) return;
#pragma unroll
    for (int r = 0; r < 3; ++r) {
        int e0 = rp[r * (NNODE + 1) + wid];
        int e1 = rp[r * (NNODE + 1) + wid + 1];
        float ax = 0.f, ay = 0.f;
        for (int e = e0; e < e1; ++e) {
            int s = col[r * NEDGE + e];
            float w = c_src[r * NNODE + s];
            ushort2 xv = xb[(size_t)s * (FIN / 2) + lane];
            ax += w * bf2f(xv.x);
            ay += w * bf2f(xv.y);
        }
        float cd = c_dst[r * NNODE + wid];
        ushort2 o;
        o.x = f2bf(ax * cd);
        o.y = f2bf(ay * cd);
        agg[(size_t)wid * (3 * FIN / 2) + r * (FIN / 2) + lane] = o;  // [N][384] bf16
    }
}

__global__ __launch_bounds__(256)
void spmm2_all(const ushort2* __restrict__ yb, const int* __restrict__ rp,
               const int* __restrict__ col, const float* __restrict__ c_src,
               const float* __restrict__ c_dst, const float2* __restrict__ b2s2,
               float2* __restrict__ out2) {
    int wid = (blockIdx.x * blockDim.x + threadIdx.x) >> 6;
    int lane = threadIdx.x & 63;
    if (wid >= NNODE) return;
    float2 acc = b2s2[lane];
#pragma unroll
    for (int r = 0; r < 3; ++r) {
        int e0 = rp[r * (NNODE + 1) + wid];
        int e1 = rp[r * (NNODE + 1) + wid + 1];
        float ax = 0.f, ay = 0.f;
        for (int e = e0; e < e1; ++e) {
            int s = col[r * NEDGE + e];
            float w = c_src[r * NNODE + s];
            ushort2 yv = yb[(size_t)s * (3 * FOUT / 2) + r * (FOUT / 2) + lane];
            ax += w * bf2f(yv.x);
            ay += w * bf2f(yv.y);
        }
        float cd = c_dst[r * NNODE + wid];
        acc.x += cd * ax;
        acc.y += cd * ay;
    }
    out2[(size_t)wid * (FOUT / 2) + lane] = acc;
}

// ------------------------------------------------------------ MFMA GEMM
// C[M][N] = A[M][K](bf16) @ B, B pre-transposed [N][K] hi/lo bf16.
// acc += A*Bh + A*Bl. 128x128 tile, BK=32, 4 waves 2x2, 4x4 frags 16x16x32.
// EPI 0: C = relu(acc + bias) -> bf16.  EPI 1: C = acc -> bf16.

template <int K, int EPI>
__global__ __launch_bounds__(256)
void gemm_bf16(const unsigned short* __restrict__ A, const unsigned short* __restrict__ Bh,
               const unsigned short* __restrict__ Bl, const float* __restrict__ bias,
               unsigned short* __restrict__ C, int M, int N) {
    __shared__ unsigned short As[128][40];
    __shared__ unsigned short Bsh[128][40];
    __shared__ unsigned short Bsl[128][40];
    const int bm = blockIdx.x * 128;
    const int bn = blockIdx.y * 128;
    const int tid = threadIdx.x;
    const int lane = tid & 63;
    const int wv = tid >> 6;
    const int wm = (wv >> 1) * 64;
    const int wn = (wv & 1) * 64;

    const int srow = tid >> 1;        // 0..127
    const int scol = (tid & 1) * 16;  // shorts
    const size_t abase = (size_t)(bm + srow) * K + scol;
    const size_t bbase = (size_t)(bn + srow) * K + scol;
    const bool avalid = (bm + srow) < M;

    f32x4 acc[4][4] = {};

    for (int k0 = 0; k0 < K; k0 += 32) {
        uint4 z = make_uint4(0, 0, 0, 0);
        uint4 a0 = z, a1 = z;
        if (avalid) {
            a0 = *(const uint4*)&A[abase + k0];
            a1 = *(const uint4*)&A[abase + k0 + 8];
        }
        uint4 b0 = *(const uint4*)&Bh[bbase + k0];
        uint4 b1 = *(const uint4*)&Bh[bbase + k0 + 8];
        uint4 m0 = *(const uint4*)&Bl[bbase + k0];
        uint4 m1 = *(const uint4*)&Bl[bbase + k0 + 8];
        *(uint4*)&As[srow][scol] = a0;
        *(uint4*)&As[srow][scol + 8] = a1;
        *(uint4*)&Bsh[srow][scol] = b0;
        *(uint4*)&Bsh[srow][scol + 8] = b1;
        *(uint4*)&Bsl[srow][scol] = m0;
        *(uint4*)&Bsl[srow][scol + 8] = m1;
        __syncthreads();

        const int kb = (lane >> 4) * 8;
        const int fr = lane & 15;
        bf16x8 a[4], bh[4], bl[4];
#pragma unroll
        for (int i = 0; i < 4; ++i) {
            a[i] = *(const bf16x8*)&As[wm + i * 16 + fr][kb];
            bh[i] = *(const bf16x8*)&Bsh[wn + i * 16 + fr][kb];
            bl[i] = *(const bf16x8*)&Bsl[wn + i * 16 + fr][kb];
        }
#pragma unroll
        for (int mi = 0; mi < 4; ++mi)
#pragma unroll
            for (int ni = 0; ni < 4; ++ni) {
                acc[mi][ni] = __builtin_amdgcn_mfma_f32_16x16x32_bf16(a[mi], bh[ni], acc[mi][ni], 0, 0, 0);
                acc[mi][ni] = __builtin_amdgcn_mfma_f32_16x16x32_bf16(a[mi], bl[ni], acc[mi][ni], 0, 0, 0);
            }
        __syncthreads();
    }

    // epilogue: C/D map col=lane&15, row=(lane>>4)*4+reg
    const int cl = lane & 15;
    const int rl = (lane >> 4) * 4;
#pragma unroll
    for (int mi = 0; mi < 4; ++mi) {
#pragma unroll
        for (int ni = 0; ni < 4; ++ni) {
            const int gcol = bn + wn + ni * 16 + cl;
            float bv = (EPI == 0) ? bias[gcol] : 0.f;
#pragma unroll
            for (int rg = 0; rg < 4; ++rg) {
                const int grow = bm + wm + mi * 16 + rl + rg;
                if (grow < M) {
                    float v = acc[mi][ni][rg];
                    if (EPI == 0) v = fmaxf(v + bv, 0.f);
                    C[(size_t)grow * N + gcol] = f2bf(v);
                }
            }
        }
    }
}

// ---------------------------------------------------------------- launcher

extern "C" void kernel_launch(void* const* d_in, const int* in_sizes, int n_in,
                              void* d_out, int out_size, void* d_ws, size_t ws_size,
                              hipStream_t stream) {
    const float* x = (const float*)d_in[0];
    const int* src_b = (const int*)d_in[1];
    const int* dst_b = (const int*)d_in[2];
    const int* src_r = (const int*)d_in[3];
    const int* dst_r = (const int*)d_in[4];
    const int* src_j = (const int*)d_in[5];
    const int* dst_j = (const int*)d_in[6];
    const float* W1[3] = {(const float*)d_in[7], (const float*)d_in[11], (const float*)d_in[15]};
    const float* b1[3] = {(const float*)d_in[8], (const float*)d_in[12], (const float*)d_in[16]};
    const float* W2[3] = {(const float*)d_in[9], (const float*)d_in[13], (const float*)d_in[17]};
    const float* b2[3] = {(const float*)d_in[10], (const float*)d_in[14], (const float*)d_in[18]};
    float* out = (float*)d_out;

    char* w = (char*)d_ws;
    auto alloc = [&](size_t bytes) -> char* {
        char* p = w;
        w += (bytes + 255) & ~(size_t)255;
        return p;
    };
    // ~172 MB total
    int* cnt = (int*)alloc((size_t)6 * NNODE * 4);  // cnt_src[3N] | cnt_dst[3N]
    int* cnt_src = cnt;
    int* cnt_dst = cnt + 3 * NNODE;
    float* c_src = (float*)alloc((size_t)3 * NNODE * 4);
    float* c_dst = (float*)alloc((size_t)3 * NNODE * 4);
    int* rp = (int*)alloc((size_t)3 * (NNODE + 1) * 4);
    int* bsum = (int*)alloc((size_t)3 * 128 * 4);
    int* rank = (int*)alloc((size_t)3 * NEDGE * 4);
    int* col = (int*)alloc((size_t)3 * NEDGE * 4);
    float* b1s = (float*)alloc(FHID * 4);
    float* b2s = (float*)alloc(FOUT * 4);
    unsigned short* xbf = (unsigned short*)alloc((size_t)NNODE * FIN * 2);       // [N][128] bf16
    unsigned short* aggcat = (unsigned short*)alloc((size_t)NNODE * 3 * FIN * 2); // [N][384] bf16
    unsigned short* ycat = aggcat;  // aliased: aggcat dead after L1 GEMM
    unsigned short* hb = (unsigned short*)alloc((size_t)NNODE * FHID * 2);       // [N][256] bf16

    // weight planes aliased over cnt (dead after scan/norms); 786 KB < 2.4 MB
    unsigned short* w1h = (unsigned short*)cnt;            // [256][384]
    unsigned short* w1l = w1h + FHID * 3 * FIN;
    unsigned short* w2h = w1l + FHID * 3 * FIN;            // [384][256]
    unsigned short* w2l = w2h + 3 * FOUT * FHID;

    const int T = 256;

    // 1. graph preprocessing
    zero_ints<<<dim3((6 * NNODE + T - 1) / T), T, 0, stream>>>(cnt, 6 * NNODE);
    degrees_kernel<<<dim3((NEDGE + T - 1) / T, 3), T, 0, stream>>>(
        src_b, dst_b, src_r, dst_r, src_j, dst_j, cnt_src, cnt_dst, rank);
    norms_kernel<<<dim3((3 * NNODE + T - 1) / T), T, 0, stream>>>(cnt_src, cnt_dst, c_src, c_dst);
    scan_phase1<<<dim3(NB, 3), 256, 0, stream>>>(cnt_dst, rp, bsum);
    scan_phase2<<<dim3(1, 3), 128, 0, stream>>>(bsum);
    scan_phase3<<<dim3(NB, 3), 256, 0, stream>>>(rp, bsum);
    scatter_kernel<<<dim3((NEDGE + T - 1) / T, 3), T, 0, stream>>>(
        src_b, dst_b, src_r, dst_r, src_j, dst_j, rank, rp, col);

    // 2. operand prep (cnt region dead now)
    x2bf_kernel<<<dim3((NNODE * FIN / 4 + T - 1) / T), T, 0, stream>>>(
        (const float4*)x, (ushort4*)xbf, NNODE * FIN / 4);
    for (int r = 0; r < 3; ++r) {
        // W1_r [128][256] -> w1t[n][r*128+k], ldt=384
        wsplit_t<<<dim3((FIN * FHID + T - 1) / T), T, 0, stream>>>(
            W1[r], w1h, w1l, FIN, FHID, 3 * FIN, 0, r * FIN);
        // W2_r [256][128] -> w2t[r*128+n][k], ldt=256
        wsplit_t<<<dim3((FHID * FOUT + T - 1) / T), T, 0, stream>>>(
            W2[r], w2h, w2l, FHID, FOUT, FHID, r * FOUT, 0);
    }
    bias_sums<<<1, 256, 0, stream>>>(b1[0], b1[1], b1[2], b2[0], b2[1], b2[2], b1s, b2s);

    const dim3 spmm_grid((NNODE * 64 + T - 1) / T);

    // 3. layer 1: aggregate all relations -> aggcat [N,384] bf16, one GEMM -> h bf16
    spmm1_all<<<spmm_grid, T, 0, stream>>>(
        (const ushort2*)xbf, rp, col, c_src, c_dst, (ushort2*)aggcat);
    gemm_bf16<3 * FIN, 0><<<dim3((NNODE + 127) / 128, FHID / 128), 256, 0, stream>>>(
        aggcat, w1h, w1l, b1s, hb, NNODE, FHID);

    // 4. layer 2: one GEMM h @ [W2_b|W2_r|W2_j] -> ycat [N,384] bf16, aggregate -> out
    gemm_bf16<FHID, 1><<<dim3((NNODE + 127) / 128, (3 * FOUT) / 128), 256, 0, stream>>>(
        hb, w2h, w2l, nullptr, ycat, NNODE, 3 * FOUT);
    spmm2_all<<<spmm_grid, T, 0, stream>>>(
        (const ushort2*)ycat, rp, col, c_src, c_dst, (const float2*)b2s, (float2*)out);
}

// Round 5
// 619.307 us; speedup vs baseline: 2.2639x; 1.2497x over previous
//
#include <hip/hip_runtime.h>
#include <hip/hip_bf16.h>
#include <cstdint>

#define NNODE 100000
#define NEDGE 500000
#define FIN   128
#define FHID  256
#define FOUT  128

typedef __attribute__((ext_vector_type(8))) short bf16x8;
typedef __attribute__((ext_vector_type(4))) float f32x4;

// ---------------------------------------------------------------- bf16 utils

__device__ inline unsigned short f2bf(float f) {
    unsigned int u = __float_as_uint(f);
    unsigned int r = (u + 0x7FFF + ((u >> 16) & 1)) >> 16;
    return (unsigned short)r;
}
__device__ inline float bf2f(unsigned short s) {
    return __uint_as_float(((unsigned int)s) << 16);
}
__device__ inline void split2(float f, unsigned short& hi, unsigned short& lo) {
    hi = f2bf(f);
    lo = f2bf(f - bf2f(hi));
}

// ---------------------------------------------------------------- utilities

__global__ void zero_ints(int* __restrict__ p, int n) {
    int i = blockIdx.x * blockDim.x + threadIdx.x;
    if (i < n) p[i] = 0;
}

// degrees + per-edge rank (rank = old count at dst — enables atomic-free scatter)
__global__ void degrees_kernel(const int* __restrict__ sb, const int* __restrict__ db,
                               const int* __restrict__ sr, const int* __restrict__ dr,
                               const int* __restrict__ sj, const int* __restrict__ dj,
                               int* __restrict__ cnt_src, int* __restrict__ cnt_dst,
                               int* __restrict__ rank) {
    int r = blockIdx.y;
    int e = blockIdx.x * blockDim.x + threadIdx.x;
    if (e >= NEDGE) return;
    const int* s = (r == 0) ? sb : (r == 1) ? sr : sj;
    const int* d = (r == 0) ? db : (r == 1) ? dr : dj;
    atomicAdd(&cnt_src[r * NNODE + s[e]], 1);
    rank[r * NEDGE + e] = atomicAdd(&cnt_dst[r * NNODE + d[e]], 1);
}

__global__ void norms_kernel(const int* __restrict__ cnt_src, const int* __restrict__ cnt_dst,
                             float* __restrict__ c_src, float* __restrict__ c_dst) {
    int i = blockIdx.x * blockDim.x + threadIdx.x;
    if (i >= 3 * NNODE) return;
    c_src[i] = rsqrtf((float)max(cnt_src[i], 1));
    c_dst[i] = rsqrtf((float)max(cnt_dst[i], 1));
}

#define SCAN_TILE 1024
#define NB 98   // ceil(100000/1024)

__global__ void scan_phase1(const int* __restrict__ cnt_dst, int* __restrict__ rp,
                            int* __restrict__ bsum) {
    int r = blockIdx.y;
    int tid = threadIdx.x;
    int idx = blockIdx.x * SCAN_TILE + tid * 4;
    int v[4];
#pragma unroll
    for (int i = 0; i < 4; ++i)
        v[i] = (idx + i < NNODE) ? cnt_dst[r * NNODE + idx + i] : 0;
    int tsum = v[0] + v[1] + v[2] + v[3];
    __shared__ int sm[256];
    sm[tid] = tsum;
    __syncthreads();
    for (int off = 1; off < 256; off <<= 1) {
        int t = 0;
        if (tid >= off) t = sm[tid - off];
        __syncthreads();
        sm[tid] += t;
        __syncthreads();
    }
    int excl = sm[tid] - tsum;
    int run = excl;
#pragma unroll
    for (int i = 0; i < 4; ++i) {
        if (idx + i < NNODE) rp[r * (NNODE + 1) + idx + i] = run;
        run += v[i];
    }
    if (tid == 255) bsum[r * 128 + blockIdx.x] = sm[255];
}

__global__ void scan_phase2(int* __restrict__ bsum) {
    int r = blockIdx.y;
    int tid = threadIdx.x;  // 128 threads
    int v = (tid < NB) ? bsum[r * 128 + tid] : 0;
    __shared__ int sm[128];
    sm[tid] = v;
    __syncthreads();
    for (int off = 1; off < 128; off <<= 1) {
        int t = 0;
        if (tid >= off) t = sm[tid - off];
        __syncthreads();
        sm[tid] += t;
        __syncthreads();
    }
    if (tid < NB) bsum[r * 128 + tid] = sm[tid] - v;
}

__global__ void scan_phase3(int* __restrict__ rp, const int* __restrict__ bsum) {
    int r = blockIdx.y;
    int tid = threadIdx.x;
    int off = bsum[r * 128 + blockIdx.x];
    int idx = blockIdx.x * SCAN_TILE + tid * 4;
#pragma unroll
    for (int i = 0; i < 4; ++i) {
        int ii = idx + i;
        if (ii < NNODE) rp[r * (NNODE + 1) + ii] += off;
    }
    if (blockIdx.x == 0 && tid == 0) rp[r * (NNODE + 1) + NNODE] = NEDGE;
}

// atomic-free scatter: col[rp[d] + rank[e]] = s
__global__ void scatter_kernel(const int* __restrict__ sb, const int* __restrict__ db,
                               const int* __restrict__ sr, const int* __restrict__ dr,
                               const int* __restrict__ sj, const int* __restrict__ dj,
                               const int* __restrict__ rank, const int* __restrict__ rp,
                               int* __restrict__ col) {
    int r = blockIdx.y;
    int e = blockIdx.x * blockDim.x + threadIdx.x;
    if (e >= NEDGE) return;
    const int* s = (r == 0) ? sb : (r == 1) ? sr : sj;
    const int* d = (r == 0) ? db : (r == 1) ? dr : dj;
    int pos = rp[r * (NNODE + 1) + d[e]] + rank[r * NEDGE + e];
    col[r * NEDGE + pos] = s[e];
}

__global__ void bias_sums(const float* __restrict__ b1b, const float* __restrict__ b1r,
                          const float* __restrict__ b1j, const float* __restrict__ b2b,
                          const float* __restrict__ b2r, const float* __restrict__ b2j,
                          float* __restrict__ b1s, float* __restrict__ b2s) {
    int i = threadIdx.x;  // 256 threads
    if (i < FHID) b1s[i] = b1b[i] + b1r[i] + b1j[i];
    if (i < FOUT) b2s[i] = b2b[i] + b2r[i] + b2j[i];
}

// x fp32 -> bf16 plane
__global__ void x2bf_kernel(const float4* __restrict__ x4, ushort4* __restrict__ xb4, int n4) {
    int i = blockIdx.x * blockDim.x + threadIdx.x;
    if (i >= n4) return;
    float4 v = x4[i];
    ushort4 o;
    o.x = f2bf(v.x);
    o.y = f2bf(v.y);
    o.z = f2bf(v.z);
    o.w = f2bf(v.w);
    xb4[i] = o;
}

// W [K][N] fp32 -> transposed hi/lo bf16 planes at th/tl[(nbase+n)*ldt + kbase + k]
__global__ void wsplit_t(const float* __restrict__ W, unsigned short* __restrict__ th,
                         unsigned short* __restrict__ tl, int K, int N, int ldt,
                         int nbase, int kbase) {
    int i = blockIdx.x * blockDim.x + threadIdx.x;
    if (i >= K * N) return;
    int k = i / N;
    int n = i - k * N;
    unsigned short hi, lo;
    split2(W[i], hi, lo);
    size_t o = (size_t)(nbase + n) * ldt + kbase + k;
    th[o] = hi;
    tl[o] = lo;
}

// --------------------------------------------------------------- SpMM (CSR)
// one wave per dst node; lane covers 2 feats (ushort2).
// MLP structure: lane-parallel col/c_src loads (1 round-trip per relation,
// broadcast via shfl), row gathers unrolled x4 for 4 loads in flight.

// generic fallback for deg > 64 chunks (rare); accumulation order preserved
__device__ inline void gather_chunk(const ushort2* __restrict__ rows, int ldrow,
                                    const int* __restrict__ colp,
                                    const float* __restrict__ csrc, int e0, int e1,
                                    int lane, float& ax, float& ay) {
    for (int base = e0; base < e1; base += 64) {
        int cnt = min(64, e1 - base);
        int sl = (lane < cnt) ? colp[base + lane] : 0;
        float wl = (lane < cnt) ? csrc[sl] : 0.f;
        int j = 0;
        for (; j + 4 <= cnt; j += 4) {
            int s0 = __shfl(sl, j), s1 = __shfl(sl, j + 1);
            int s2 = __shfl(sl, j + 2), s3 = __shfl(sl, j + 3);
            float w0 = __shfl(wl, j), w1 = __shfl(wl, j + 1);
            float w2 = __shfl(wl, j + 2), w3 = __shfl(wl, j + 3);
            ushort2 v0 = rows[(size_t)s0 * ldrow + lane];
            ushort2 v1 = rows[(size_t)s1 * ldrow + lane];
            ushort2 v2 = rows[(size_t)s2 * ldrow + lane];
            ushort2 v3 = rows[(size_t)s3 * ldrow + lane];
            ax += w0 * bf2f(v0.x); ay += w0 * bf2f(v0.y);
            ax += w1 * bf2f(v1.x); ay += w1 * bf2f(v1.y);
            ax += w2 * bf2f(v2.x); ay += w2 * bf2f(v2.y);
            ax += w3 * bf2f(v3.x); ay += w3 * bf2f(v3.y);
        }
        for (; j < cnt; ++j) {
            int s = __shfl(sl, j);
            float w = __shfl(wl, j);
            ushort2 v = rows[(size_t)s * ldrow + lane];
            ax += w * bf2f(v.x); ay += w * bf2f(v.y);
        }
    }
}

__global__ __launch_bounds__(256)
void spmm1_all(const ushort2* __restrict__ xb, const int* __restrict__ rp,
               const int* __restrict__ col, const float* __restrict__ c_src,
               const float* __restrict__ c_dst, ushort2* __restrict__ agg) {
    int wid = (blockIdx.x * blockDim.x + threadIdx.x) >> 6;
    int lane = threadIdx.x & 63;
    if (wid >= NNODE) return;
    int e0[3], e1[3], sl[3];
    float wl[3];
#pragma unroll
    for (int r = 0; r < 3; ++r) {
        e0[r] = rp[r * (NNODE + 1) + wid];
        e1[r] = rp[r * (NNODE + 1) + wid + 1];
    }
#pragma unroll
    for (int r = 0; r < 3; ++r) {
        int cnt = min(e1[r] - e0[r], 64);
        sl[r] = (lane < cnt) ? col[r * NEDGE + e0[r] + lane] : 0;
    }
#pragma unroll
    for (int r = 0; r < 3; ++r) {
        int cnt = min(e1[r] - e0[r], 64);
        wl[r] = (lane < cnt) ? c_src[r * NNODE + sl[r]] : 0.f;
    }
#pragma unroll
    for (int r = 0; r < 3; ++r) {
        float ax = 0.f, ay = 0.f;
        int cnt = min(e1[r] - e0[r], 64);
        int j = 0;
        for (; j + 4 <= cnt; j += 4) {
            int s0 = __shfl(sl[r], j), s1 = __shfl(sl[r], j + 1);
            int s2 = __shfl(sl[r], j + 2), s3 = __shfl(sl[r], j + 3);
            float w0 = __shfl(wl[r], j), w1 = __shfl(wl[r], j + 1);
            float w2 = __shfl(wl[r], j + 2), w3 = __shfl(wl[r], j + 3);
            ushort2 v0 = xb[(size_t)s0 * (FIN / 2) + lane];
            ushort2 v1 = xb[(size_t)s1 * (FIN / 2) + lane];
            ushort2 v2 = xb[(size_t)s2 * (FIN / 2) + lane];
            ushort2 v3 = xb[(size_t)s3 * (FIN / 2) + lane];
            ax += w0 * bf2f(v0.x); ay += w0 * bf2f(v0.y);
            ax += w1 * bf2f(v1.x); ay += w1 * bf2f(v1.y);
            ax += w2 * bf2f(v2.x); ay += w2 * bf2f(v2.y);
            ax += w3 * bf2f(v3.x); ay += w3 * bf2f(v3.y);
        }
        for (; j < cnt; ++j) {
            int s = __shfl(sl[r], j);
            float w = __shfl(wl[r], j);
            ushort2 v = xb[(size_t)s * (FIN / 2) + lane];
            ax += w * bf2f(v.x); ay += w * bf2f(v.y);
        }
        if (e0[r] + 64 < e1[r])
            gather_chunk(xb, FIN / 2, col + (size_t)r * NEDGE, c_src + r * NNODE,
                         e0[r] + 64, e1[r], lane, ax, ay);
        float cd = c_dst[r * NNODE + wid];
        ushort2 o;
        o.x = f2bf(ax * cd);
        o.y = f2bf(ay * cd);
        agg[(size_t)wid * (3 * FIN / 2) + r * (FIN / 2) + lane] = o;  // [N][384] bf16
    }
}

__global__ __launch_bounds__(256)
void spmm2_all(const ushort2* __restrict__ yb, const int* __restrict__ rp,
               const int* __restrict__ col, const float* __restrict__ c_src,
               const float* __restrict__ c_dst, const float2* __restrict__ b2s2,
               float2* __restrict__ out2) {
    int wid = (blockIdx.x * blockDim.x + threadIdx.x) >> 6;
    int lane = threadIdx.x & 63;
    if (wid >= NNODE) return;
    int e0[3], e1[3], sl[3];
    float wl[3];
#pragma unroll
    for (int r = 0; r < 3; ++r) {
        e0[r] = rp[r * (NNODE + 1) + wid];
        e1[r] = rp[r * (NNODE + 1) + wid + 1];
    }
#pragma unroll
    for (int r = 0; r < 3; ++r) {
        int cnt = min(e1[r] - e0[r], 64);
        sl[r] = (lane < cnt) ? col[r * NEDGE + e0[r] + lane] : 0;
    }
#pragma unroll
    for (int r = 0; r < 3; ++r) {
        int cnt = min(e1[r] - e0[r], 64);
        wl[r] = (lane < cnt) ? c_src[r * NNODE + sl[r]] : 0.f;
    }
    float2 acc = b2s2[lane];
#pragma unroll
    for (int r = 0; r < 3; ++r) {
        const ushort2* rows = yb + r * (FOUT / 2);  // row stride 3*FOUT/2
        float ax = 0.f, ay = 0.f;
        int cnt = min(e1[r] - e0[r], 64);
        int j = 0;
        for (; j + 4 <= cnt; j += 4) {
            int s0 = __shfl(sl[r], j), s1 = __shfl(sl[r], j + 1);
            int s2 = __shfl(sl[r], j + 2), s3 = __shfl(sl[r], j + 3);
            float w0 = __shfl(wl[r], j), w1 = __shfl(wl[r], j + 1);
            float w2 = __shfl(wl[r], j + 2), w3 = __shfl(wl[r], j + 3);
            ushort2 v0 = rows[(size_t)s0 * (3 * FOUT / 2) + lane];
            ushort2 v1 = rows[(size_t)s1 * (3 * FOUT / 2) + lane];
            ushort2 v2 = rows[(size_t)s2 * (3 * FOUT / 2) + lane];
            ushort2 v3 = rows[(size_t)s3 * (3 * FOUT / 2) + lane];
            ax += w0 * bf2f(v0.x); ay += w0 * bf2f(v0.y);
            ax += w1 * bf2f(v1.x); ay += w1 * bf2f(v1.y);
            ax += w2 * bf2f(v2.x); ay += w2 * bf2f(v2.y);
            ax += w3 * bf2f(v3.x); ay += w3 * bf2f(v3.y);
        }
        for (; j < cnt; ++j) {
            int s = __shfl(sl[r], j);
            float w = __shfl(wl[r], j);
            ushort2 v = rows[(size_t)s * (3 * FOUT / 2) + lane];
            ax += w * bf2f(v.x); ay += w * bf2f(v.y);
        }
        if (e0[r] + 64 < e1[r])
            gather_chunk(rows, 3 * FOUT / 2, col + (size_t)r * NEDGE, c_src + r * NNODE,
                         e0[r] + 64, e1[r], lane, ax, ay);
        float cd = c_dst[r * NNODE + wid];
        acc.x += cd * ax;
        acc.y += cd * ay;
    }
    out2[(size_t)wid * (FOUT / 2) + lane] = acc;
}

// ------------------------------------------------------------ MFMA GEMM
// C[M][N] = A[M][K](bf16) @ B, B pre-transposed [N][K] hi/lo bf16.
// acc += A*Bh + A*Bl. 128x128 tile, BK=32, 4 waves 2x2, 4x4 frags 16x16x32.
// EPI 0: C = relu(acc + bias) -> bf16.  EPI 1: C = acc -> bf16.

template <int K, int EPI>
__global__ __launch_bounds__(256)
void gemm_bf16(const unsigned short* __restrict__ A, const unsigned short* __restrict__ Bh,
               const unsigned short* __restrict__ Bl, const float* __restrict__ bias,
               unsigned short* __restrict__ C, int M, int N) {
    __shared__ unsigned short As[128][40];
    __shared__ unsigned short Bsh[128][40];
    __shared__ unsigned short Bsl[128][40];
    const int bm = blockIdx.x * 128;
    const int bn = blockIdx.y * 128;
    const int tid = threadIdx.x;
    const int lane = tid & 63;
    const int wv = tid >> 6;
    const int wm = (wv >> 1) * 64;
    const int wn = (wv & 1) * 64;

    const int srow = tid >> 1;        // 0..127
    const int scol = (tid & 1) * 16;  // shorts
    const size_t abase = (size_t)(bm + srow) * K + scol;
    const size_t bbase = (size_t)(bn + srow) * K + scol;
    const bool avalid = (bm + srow) < M;

    f32x4 acc[4][4] = {};

    for (int k0 = 0; k0 < K; k0 += 32) {
        uint4 z = make_uint4(0, 0, 0, 0);
        uint4 a0 = z, a1 = z;
        if (avalid) {
            a0 = *(const uint4*)&A[abase + k0];
            a1 = *(const uint4*)&A[abase + k0 + 8];
        }
        uint4 b0 = *(const uint4*)&Bh[bbase + k0];
        uint4 b1 = *(const uint4*)&Bh[bbase + k0 + 8];
        uint4 m0 = *(const uint4*)&Bl[bbase + k0];
        uint4 m1 = *(const uint4*)&Bl[bbase + k0 + 8];
        *(uint4*)&As[srow][scol] = a0;
        *(uint4*)&As[srow][scol + 8] = a1;
        *(uint4*)&Bsh[srow][scol] = b0;
        *(uint4*)&Bsh[srow][scol + 8] = b1;
        *(uint4*)&Bsl[srow][scol] = m0;
        *(uint4*)&Bsl[srow][scol + 8] = m1;
        __syncthreads();

        const int kb = (lane >> 4) * 8;
        const int fr = lane & 15;
        bf16x8 a[4], bh[4], bl[4];
#pragma unroll
        for (int i = 0; i < 4; ++i) {
            a[i] = *(const bf16x8*)&As[wm + i * 16 + fr][kb];
            bh[i] = *(const bf16x8*)&Bsh[wn + i * 16 + fr][kb];
            bl[i] = *(const bf16x8*)&Bsl[wn + i * 16 + fr][kb];
        }
#pragma unroll
        for (int mi = 0; mi < 4; ++mi)
#pragma unroll
            for (int ni = 0; ni < 4; ++ni) {
                acc[mi][ni] = __builtin_amdgcn_mfma_f32_16x16x32_bf16(a[mi], bh[ni], acc[mi][ni], 0, 0, 0);
                acc[mi][ni] = __builtin_amdgcn_mfma_f32_16x16x32_bf16(a[mi], bl[ni], acc[mi][ni], 0, 0, 0);
            }
        __syncthreads();
    }

    // epilogue: C/D map col=lane&15, row=(lane>>4)*4+reg
    const int cl = lane & 15;
    const int rl = (lane >> 4) * 4;
#pragma unroll
    for (int mi = 0; mi < 4; ++mi) {
#pragma unroll
        for (int ni = 0; ni < 4; ++ni) {
            const int gcol = bn + wn + ni * 16 + cl;
            float bv = (EPI == 0) ? bias[gcol] : 0.f;
#pragma unroll
            for (int rg = 0; rg < 4; ++rg) {
                const int grow = bm + wm + mi * 16 + rl + rg;
                if (grow < M) {
                    float v = acc[mi][ni][rg];
                    if (EPI == 0) v = fmaxf(v + bv, 0.f);
                    C[(size_t)grow * N + gcol] = f2bf(v);
                }
            }
        }
    }
}

// ---------------------------------------------------------------- launcher

extern "C" void kernel_launch(void* const* d_in, const int* in_sizes, int n_in,
                              void* d_out, int out_size, void* d_ws, size_t ws_size,
                              hipStream_t stream) {
    const float* x = (const float*)d_in[0];
    const int* src_b = (const int*)d_in[1];
    const int* dst_b = (const int*)d_in[2];
    const int* src_r = (const int*)d_in[3];
    const int* dst_r = (const int*)d_in[4];
    const int* src_j = (const int*)d_in[5];
    const int* dst_j = (const int*)d_in[6];
    const float* W1[3] = {(const float*)d_in[7], (const float*)d_in[11], (const float*)d_in[15]};
    const float* b1[3] = {(const float*)d_in[8], (const float*)d_in[12], (const float*)d_in[16]};
    const float* W2[3] = {(const float*)d_in[9], (const float*)d_in[13], (const float*)d_in[17]};
    const float* b2[3] = {(const float*)d_in[10], (const float*)d_in[14], (const float*)d_in[18]};
    float* out = (float*)d_out;

    char* w = (char*)d_ws;
    auto alloc = [&](size_t bytes) -> char* {
        char* p = w;
        w += (bytes + 255) & ~(size_t)255;
        return p;
    };
    // ~172 MB total
    int* cnt = (int*)alloc((size_t)6 * NNODE * 4);  // cnt_src[3N] | cnt_dst[3N]
    int* cnt_src = cnt;
    int* cnt_dst = cnt + 3 * NNODE;
    float* c_src = (float*)alloc((size_t)3 * NNODE * 4);
    float* c_dst = (float*)alloc((size_t)3 * NNODE * 4);
    int* rp = (int*)alloc((size_t)3 * (NNODE + 1) * 4);
    int* bsum = (int*)alloc((size_t)3 * 128 * 4);
    int* rank = (int*)alloc((size_t)3 * NEDGE * 4);
    int* col = (int*)alloc((size_t)3 * NEDGE * 4);
    float* b1s = (float*)alloc(FHID * 4);
    float* b2s = (float*)alloc(FOUT * 4);
    unsigned short* xbf = (unsigned short*)alloc((size_t)NNODE * FIN * 2);       // [N][128] bf16
    unsigned short* aggcat = (unsigned short*)alloc((size_t)NNODE * 3 * FIN * 2); // [N][384] bf16
    unsigned short* ycat = aggcat;  // aliased: aggcat dead after L1 GEMM
    unsigned short* hb = (unsigned short*)alloc((size_t)NNODE * FHID * 2);       // [N][256] bf16

    // weight planes aliased over cnt (dead after scan/norms); 786 KB < 2.4 MB
    unsigned short* w1h = (unsigned short*)cnt;            // [256][384]
    unsigned short* w1l = w1h + FHID * 3 * FIN;
    unsigned short* w2h = w1l + FHID * 3 * FIN;            // [384][256]
    unsigned short* w2l = w2h + 3 * FOUT * FHID;

    const int T = 256;

    // 1. graph preprocessing
    zero_ints<<<dim3((6 * NNODE + T - 1) / T), T, 0, stream>>>(cnt, 6 * NNODE);
    degrees_kernel<<<dim3((NEDGE + T - 1) / T, 3), T, 0, stream>>>(
        src_b, dst_b, src_r, dst_r, src_j, dst_j, cnt_src, cnt_dst, rank);
    norms_kernel<<<dim3((3 * NNODE + T - 1) / T), T, 0, stream>>>(cnt_src, cnt_dst, c_src, c_dst);
    scan_phase1<<<dim3(NB, 3), 256, 0, stream>>>(cnt_dst, rp, bsum);
    scan_phase2<<<dim3(1, 3), 128, 0, stream>>>(bsum);
    scan_phase3<<<dim3(NB, 3), 256, 0, stream>>>(rp, bsum);
    scatter_kernel<<<dim3((NEDGE + T - 1) / T, 3), T, 0, stream>>>(
        src_b, dst_b, src_r, dst_r, src_j, dst_j, rank, rp, col);

    // 2. operand prep (cnt region dead now)
    x2bf_kernel<<<dim3((NNODE * FIN / 4 + T - 1) / T), T, 0, stream>>>(
        (const float4*)x, (ushort4*)xbf, NNODE * FIN / 4);
    for (int r = 0; r < 3; ++r) {
        // W1_r [128][256] -> w1t[n][r*128+k], ldt=384
        wsplit_t<<<dim3((FIN * FHID + T - 1) / T), T, 0, stream>>>(
            W1[r], w1h, w1l, FIN, FHID, 3 * FIN, 0, r * FIN);
        // W2_r [256][128] -> w2t[r*128+n][k], ldt=256
        wsplit_t<<<dim3((FHID * FOUT + T - 1) / T), T, 0, stream>>>(
            W2[r], w2h, w2l, FHID, FOUT, FHID, r * FOUT, 0);
    }
    bias_sums<<<1, 256, 0, stream>>>(b1[0], b1[1], b1[2], b2[0], b2[1], b2[2], b1s, b2s);

    const dim3 spmm_grid((NNODE * 64 + T - 1) / T);

    // 3. layer 1: aggregate all relations -> aggcat [N,384] bf16, one GEMM -> h bf16
    spmm1_all<<<spmm_grid, T, 0, stream>>>(
        (const ushort2*)xbf, rp, col, c_src, c_dst, (ushort2*)aggcat);
    gemm_bf16<3 * FIN, 0><<<dim3((NNODE + 127) / 128, FHID / 128), 256, 0, stream>>>(
        aggcat, w1h, w1l, b1s, hb, NNODE, FHID);

    // 4. layer 2: one GEMM h @ [W2_b|W2_r|W2_j] -> ycat [N,384] bf16, aggregate -> out
    gemm_bf16<FHID, 1><<<dim3((NNODE + 127) / 128, (3 * FOUT) / 128), 256, 0, stream>>>(
        hb, w2h, w2l, nullptr, ycat, NNODE, 3 * FOUT);
    spmm2_all<<<spmm_grid, T, 0, stream>>>(
        (const ushort2*)ycat, rp, col, c_src, c_dst, (const float2*)b2s, (float2*)out);
}

// Round 6
// 534.016 us; speedup vs baseline: 2.6255x; 1.1597x over previous
//
#include <hip/hip_runtime.h>
#include <hip/hip_bf16.h>
#include <cstdint>

#define NNODE 100000
#define NEDGE 500000
#define FIN   128
#define FHID  256
#define FOUT  128

// bucket-sort CSR parameters
#define NBUCK  1563   // ceil(NNODE/64)
#define CHUNK  2048
#define NCHUNK 245    // ceil(NEDGE/CHUNK)

typedef __attribute__((ext_vector_type(8))) short bf16x8;
typedef __attribute__((ext_vector_type(4))) float f32x4;

// ---------------------------------------------------------------- bf16 utils

__device__ inline unsigned short f2bf(float f) {
    unsigned int u = __float_as_uint(f);
    unsigned int r = (u + 0x7FFF + ((u >> 16) & 1)) >> 16;
    return (unsigned short)r;
}
__device__ inline float bf2f(unsigned short s) {
    return __uint_as_float(((unsigned int)s) << 16);
}
__device__ inline void split2(float f, unsigned short& hi, unsigned short& lo) {
    hi = f2bf(f);
    lo = f2bf(f - bf2f(hi));
}

// ------------------------------------------------ atomic-free CSR build
// All coordination via LDS atomics; zero global atomics (each global atomic
// costs a ~32B memory-side round trip; 3M of them was 150us in prior rounds).

// P1: per-chunk LDS histograms over 64-node buckets (dst and src together)
__global__ __launch_bounds__(256)
void csr_count(const int* __restrict__ sb, const int* __restrict__ db,
               const int* __restrict__ sr, const int* __restrict__ dr,
               const int* __restrict__ sj, const int* __restrict__ dj,
               int* __restrict__ bh_dst, int* __restrict__ bh_src) {
    __shared__ int h1[NBUCK], h2[NBUCK];
    const int r = blockIdx.y, c = blockIdx.x, tid = threadIdx.x;
    const int* s = (r == 0) ? sb : (r == 1) ? sr : sj;
    const int* d = (r == 0) ? db : (r == 1) ? dr : dj;
    for (int i = tid; i < NBUCK; i += 256) { h1[i] = 0; h2[i] = 0; }
    __syncthreads();
    const int e0 = c * CHUNK;
#pragma unroll
    for (int i = 0; i < CHUNK / 256; ++i) {
        int e = e0 + i * 256 + tid;
        if (e < NEDGE) {
            atomicAdd(&h1[d[e] >> 6], 1);
            atomicAdd(&h2[s[e] >> 6], 1);
        }
    }
    __syncthreads();
    int* o1 = bh_dst + ((size_t)r * NCHUNK + c) * NBUCK;
    int* o2 = bh_src + ((size_t)r * NCHUNK + c) * NBUCK;
    for (int i = tid; i < NBUCK; i += 256) { o1[i] = h1[i]; o2[i] = h2[i]; }
}

// P2a: in-place exclusive scan over chunks (per bucket); emits bucket totals
__global__ void csr_scan_chunks(int* __restrict__ bh_dst, int* __restrict__ bh_src,
                                int* __restrict__ tot) {
    int idx = blockIdx.x * blockDim.x + threadIdx.x;
    if (idx >= 2 * 3 * NBUCK) return;
    int k = idx / (3 * NBUCK);
    int rem = idx - k * 3 * NBUCK;
    int r = rem / NBUCK;
    int b = rem - r * NBUCK;
    int* p = ((k == 0) ? bh_dst : bh_src) + (size_t)r * NCHUNK * NBUCK + b;
    int t = 0;
    int c = 0;
    for (; c + 4 <= NCHUNK; c += 4) {   // x4 unroll: 4 loads in flight
        int v0 = p[0], v1 = p[NBUCK], v2 = p[2 * NBUCK], v3 = p[3 * NBUCK];
        p[0] = t; t += v0;
        p[NBUCK] = t; t += v1;
        p[2 * NBUCK] = t; t += v2;
        p[3 * NBUCK] = t; t += v3;
        p += 4 * NBUCK;
    }
    for (; c < NCHUNK; ++c) { int v = *p; *p = t; t += v; p += NBUCK; }
    tot[(k * 3 + r) * NBUCK + b] = t;
}

// P2b: exclusive scan over buckets -> bucket bases (incl. total at [NBUCK])
__global__ void csr_scan_buckets(const int* __restrict__ tot, int* __restrict__ bb) {
    const int k = blockIdx.x, r = blockIdx.y, tid = threadIdx.x;  // 256 thr
    const int base_in = (k * 3 + r) * NBUCK;
    const int base_out = (k * 3 + r) * (NBUCK + 1);
    int v[8];
    const int idx0 = tid * 8;
    int tsum = 0;
#pragma unroll
    for (int i = 0; i < 8; ++i) {
        int ii = idx0 + i;
        v[i] = (ii < NBUCK) ? tot[base_in + ii] : 0;
        tsum += v[i];
    }
    __shared__ int sm[256];
    sm[tid] = tsum;
    __syncthreads();
    for (int off = 1; off < 256; off <<= 1) {
        int t = 0;
        if (tid >= off) t = sm[tid - off];
        __syncthreads();
        sm[tid] += t;
        __syncthreads();
    }
    int run = sm[tid] - tsum;
#pragma unroll
    for (int i = 0; i < 8; ++i) {
        int ii = idx0 + i;
        if (ii <= NBUCK) bb[base_out + ii] = run;
        run += v[i];
    }
}

// P3: scatter edges into bucket-grouped buffers (LDS cursors, disjoint ranges)
__global__ __launch_bounds__(256)
void csr_scatter(const int* __restrict__ sb, const int* __restrict__ db,
                 const int* __restrict__ sr, const int* __restrict__ dr,
                 const int* __restrict__ sj, const int* __restrict__ dj,
                 const int* __restrict__ bh_dst, const int* __restrict__ bh_src,
                 const int* __restrict__ bb, unsigned int* __restrict__ ebd,
                 unsigned char* __restrict__ ebs) {
    __shared__ int cur1[NBUCK], cur2[NBUCK];
    const int r = blockIdx.y, c = blockIdx.x, tid = threadIdx.x;
    const int* s = (r == 0) ? sb : (r == 1) ? sr : sj;
    const int* d = (r == 0) ? db : (r == 1) ? dr : dj;
    const int* p1 = bh_dst + ((size_t)r * NCHUNK + c) * NBUCK;
    const int* p2 = bh_src + ((size_t)r * NCHUNK + c) * NBUCK;
    const int* bb1 = bb + r * (NBUCK + 1);              // dst section (k=0)
    const int* bb2 = bb + (3 + r) * (NBUCK + 1);        // src section (k=1)
    for (int i = tid; i < NBUCK; i += 256) {
        cur1[i] = bb1[i] + p1[i];
        cur2[i] = bb2[i] + p2[i];
    }
    __syncthreads();
    const int e0 = c * CHUNK;
#pragma unroll
    for (int i = 0; i < CHUNK / 256; ++i) {
        int e = e0 + i * 256 + tid;
        if (e < NEDGE) {
            int dv = d[e], sv = s[e];
            int q1 = atomicAdd(&cur1[dv >> 6], 1);
            ebd[(size_t)r * NEDGE + q1] = ((unsigned)(dv & 63) << 17) | (unsigned)sv;
            int q2 = atomicAdd(&cur2[sv >> 6], 1);
            ebs[(size_t)r * NEDGE + q2] = (unsigned char)(sv & 63);
        }
    }
}

// P4dst: per-bucket histogram -> cnt_dst + rp (direct), scatter -> col
__global__ __launch_bounds__(256)
void csr_finalize_dst(const unsigned int* __restrict__ ebd, const int* __restrict__ bb,
                      int* __restrict__ cnt_dst, int* __restrict__ rp,
                      int* __restrict__ col) {
    __shared__ int hist[64], pref[64], cur[64];
    const int b = blockIdx.x, r = blockIdx.y, tid = threadIdx.x;
    const int* bb1 = bb + r * (NBUCK + 1);
    const int seg0 = bb1[b], seg1 = bb1[b + 1];
    if (tid < 64) hist[tid] = 0;
    __syncthreads();
    const unsigned int* eb = ebd + (size_t)r * NEDGE;
    for (int e = seg0 + tid; e < seg1; e += 256)
        atomicAdd(&hist[eb[e] >> 17], 1);
    __syncthreads();
    if (tid == 0) {
        int run = 0;
        for (int i = 0; i < 64; ++i) { pref[i] = run; run += hist[i]; }
    }
    __syncthreads();
    if (tid < 64) {
        int node = b * 64 + tid;
        if (node < NNODE) {
            cnt_dst[r * NNODE + node] = hist[tid];
            rp[r * (NNODE + 1) + node] = seg0 + pref[tid];
        }
        cur[tid] = seg0 + pref[tid];
    }
    if (b == 0 && tid == 0) rp[r * (NNODE + 1) + NNODE] = NEDGE;
    __syncthreads();
    for (int e = seg0 + tid; e < seg1; e += 256) {
        unsigned int key = eb[e];
        int pos = atomicAdd(&cur[key >> 17], 1);
        col[(size_t)r * NEDGE + pos] = (int)(key & 0x1FFFF);
    }
}

// P4src: per-bucket byte histogram -> cnt_src
__global__ __launch_bounds__(256)
void csr_count_src(const unsigned char* __restrict__ ebs, const int* __restrict__ bbs,
                   int* __restrict__ cnt_src) {
    __shared__ int hist[64];
    const int b = blockIdx.x, r = blockIdx.y, tid = threadIdx.x;
    const int* bb2 = bbs + r * (NBUCK + 1);
    const int seg0 = bb2[b], seg1 = bb2[b + 1];
    if (tid < 64) hist[tid] = 0;
    __syncthreads();
    const unsigned char* eb = ebs + (size_t)r * NEDGE;
    for (int e = seg0 + tid; e < seg1; e += 256)
        atomicAdd(&hist[eb[e]], 1);
    __syncthreads();
    if (tid < 64) {
        int node = b * 64 + tid;
        if (node < NNODE) cnt_src[r * NNODE + node] = hist[tid];
    }
}

// ---------------------------------------------------------------- norms etc.

__global__ void norms_kernel(const int* __restrict__ cnt_src, const int* __restrict__ cnt_dst,
                             float* __restrict__ c_src, float* __restrict__ c_dst) {
    int i = blockIdx.x * blockDim.x + threadIdx.x;
    if (i >= 3 * NNODE) return;
    c_src[i] = rsqrtf((float)max(cnt_src[i], 1));
    c_dst[i] = rsqrtf((float)max(cnt_dst[i], 1));
}

__global__ void bias_sums(const float* __restrict__ b1b, const float* __restrict__ b1r,
                          const float* __restrict__ b1j, const float* __restrict__ b2b,
                          const float* __restrict__ b2r, const float* __restrict__ b2j,
                          float* __restrict__ b1s, float* __restrict__ b2s) {
    int i = threadIdx.x;  // 256 threads
    if (i < FHID) b1s[i] = b1b[i] + b1r[i] + b1j[i];
    if (i < FOUT) b2s[i] = b2b[i] + b2r[i] + b2j[i];
}

// x fp32 -> bf16 plane
__global__ void x2bf_kernel(const float4* __restrict__ x4, ushort4* __restrict__ xb4, int n4) {
    int i = blockIdx.x * blockDim.x + threadIdx.x;
    if (i >= n4) return;
    float4 v = x4[i];
    ushort4 o;
    o.x = f2bf(v.x);
    o.y = f2bf(v.y);
    o.z = f2bf(v.z);
    o.w = f2bf(v.w);
    xb4[i] = o;
}

// W [K][N] fp32 -> transposed hi/lo bf16 planes at th/tl[(nbase+n)*ldt + kbase + k]
__global__ void wsplit_t(const float* __restrict__ W, unsigned short* __restrict__ th,
                         unsigned short* __restrict__ tl, int K, int N, int ldt,
                         int nbase, int kbase) {
    int i = blockIdx.x * blockDim.x + threadIdx.x;
    if (i >= K * N) return;
    int k = i / N;
    int n = i - k * N;
    unsigned short hi, lo;
    split2(W[i], hi, lo);
    size_t o = (size_t)(nbase + n) * ldt + kbase + k;
    th[o] = hi;
    tl[o] = lo;
}

// --------------------------------------------------------------- SpMM (CSR)
// one wave per dst node; lane covers 2 feats (ushort2).
// lane-parallel col/c_src loads (1 round-trip per relation, broadcast via
// shfl), row gathers unrolled x4 for 4 loads in flight.

__device__ inline void gather_chunk(const ushort2* __restrict__ rows, int ldrow,
                                    const int* __restrict__ colp,
                                    const float* __restrict__ csrc, int e0, int e1,
                                    int lane, float& ax, float& ay) {
    for (int base = e0; base < e1; base += 64) {
        int cnt = min(64, e1 - base);
        int sl = (lane < cnt) ? colp[base + lane] : 0;
        float wl = (lane < cnt) ? csrc[sl] : 0.f;
        int j = 0;
        for (; j + 4 <= cnt; j += 4) {
            int s0 = __shfl(sl, j), s1 = __shfl(sl, j + 1);
            int s2 = __shfl(sl, j + 2), s3 = __shfl(sl, j + 3);
            float w0 = __shfl(wl, j), w1 = __shfl(wl, j + 1);
            float w2 = __shfl(wl, j + 2), w3 = __shfl(wl, j + 3);
            ushort2 v0 = rows[(size_t)s0 * ldrow + lane];
            ushort2 v1 = rows[(size_t)s1 * ldrow + lane];
            ushort2 v2 = rows[(size_t)s2 * ldrow + lane];
            ushort2 v3 = rows[(size_t)s3 * ldrow + lane];
            ax += w0 * bf2f(v0.x); ay += w0 * bf2f(v0.y);
            ax += w1 * bf2f(v1.x); ay += w1 * bf2f(v1.y);
            ax += w2 * bf2f(v2.x); ay += w2 * bf2f(v2.y);
            ax += w3 * bf2f(v3.x); ay += w3 * bf2f(v3.y);
        }
        for (; j < cnt; ++j) {
            int s = __shfl(sl, j);
            float w = __shfl(wl, j);
            ushort2 v = rows[(size_t)s * ldrow + lane];
            ax += w * bf2f(v.x); ay += w * bf2f(v.y);
        }
    }
}

__global__ __launch_bounds__(256)
void spmm1_all(const ushort2* __restrict__ xb, const int* __restrict__ rp,
               const int* __restrict__ col, const float* __restrict__ c_src,
               const float* __restrict__ c_dst, ushort2* __restrict__ agg) {
    int wid = (blockIdx.x * blockDim.x + threadIdx.x) >> 6;
    int lane = threadIdx.x & 63;
    if (wid >= NNODE) return;
    int e0[3], e1[3], sl[3];
    float wl[3];
#pragma unroll
    for (int r = 0; r < 3; ++r) {
        e0[r] = rp[r * (NNODE + 1) + wid];
        e1[r] = rp[r * (NNODE + 1) + wid + 1];
    }
#pragma unroll
    for (int r = 0; r < 3; ++r) {
        int cnt = min(e1[r] - e0[r], 64);
        sl[r] = (lane < cnt) ? col[r * NEDGE + e0[r] + lane] : 0;
    }
#pragma unroll
    for (int r = 0; r < 3; ++r) {
        int cnt = min(e1[r] - e0[r], 64);
        wl[r] = (lane < cnt) ? c_src[r * NNODE + sl[r]] : 0.f;
    }
#pragma unroll
    for (int r = 0; r < 3; ++r) {
        float ax = 0.f, ay = 0.f;
        int cnt = min(e1[r] - e0[r], 64);
        int j = 0;
        for (; j + 4 <= cnt; j += 4) {
            int s0 = __shfl(sl[r], j), s1 = __shfl(sl[r], j + 1);
            int s2 = __shfl(sl[r], j + 2), s3 = __shfl(sl[r], j + 3);
            float w0 = __shfl(wl[r], j), w1 = __shfl(wl[r], j + 1);
            float w2 = __shfl(wl[r], j + 2), w3 = __shfl(wl[r], j + 3);
            ushort2 v0 = xb[(size_t)s0 * (FIN / 2) + lane];
            ushort2 v1 = xb[(size_t)s1 * (FIN / 2) + lane];
            ushort2 v2 = xb[(size_t)s2 * (FIN / 2) + lane];
            ushort2 v3 = xb[(size_t)s3 * (FIN / 2) + lane];
            ax += w0 * bf2f(v0.x); ay += w0 * bf2f(v0.y);
            ax += w1 * bf2f(v1.x); ay += w1 * bf2f(v1.y);
            ax += w2 * bf2f(v2.x); ay += w2 * bf2f(v2.y);
            ax += w3 * bf2f(v3.x); ay += w3 * bf2f(v3.y);
        }
        for (; j < cnt; ++j) {
            int s = __shfl(sl[r], j);
            float w = __shfl(wl[r], j);
            ushort2 v = xb[(size_t)s * (FIN / 2) + lane];
            ax += w * bf2f(v.x); ay += w * bf2f(v.y);
        }
        if (e0[r] + 64 < e1[r])
            gather_chunk(xb, FIN / 2, col + (size_t)r * NEDGE, c_src + r * NNODE,
                         e0[r] + 64, e1[r], lane, ax, ay);
        float cd = c_dst[r * NNODE + wid];
        ushort2 o;
        o.x = f2bf(ax * cd);
        o.y = f2bf(ay * cd);
        agg[(size_t)wid * (3 * FIN / 2) + r * (FIN / 2) + lane] = o;  // [N][384] bf16
    }
}

__global__ __launch_bounds__(256)
void spmm2_all(const ushort2* __restrict__ yb, const int* __restrict__ rp,
               const int* __restrict__ col, const float* __restrict__ c_src,
               const float* __restrict__ c_dst, const float2* __restrict__ b2s2,
               float2* __restrict__ out2) {
    int wid = (blockIdx.x * blockDim.x + threadIdx.x) >> 6;
    int lane = threadIdx.x & 63;
    if (wid >= NNODE) return;
    int e0[3], e1[3], sl[3];
    float wl[3];
#pragma unroll
    for (int r = 0; r < 3; ++r) {
        e0[r] = rp[r * (NNODE + 1) + wid];
        e1[r] = rp[r * (NNODE + 1) + wid + 1];
    }
#pragma unroll
    for (int r = 0; r < 3; ++r) {
        int cnt = min(e1[r] - e0[r], 64);
        sl[r] = (lane < cnt) ? col[r * NEDGE + e0[r] + lane] : 0;
    }
#pragma unroll
    for (int r = 0; r < 3; ++r) {
        int cnt = min(e1[r] - e0[r], 64);
        wl[r] = (lane < cnt) ? c_src[r * NNODE + sl[r]] : 0.f;
    }
    float2 acc = b2s2[lane];
#pragma unroll
    for (int r = 0; r < 3; ++r) {
        const ushort2* rows = yb + r * (FOUT / 2);  // row stride 3*FOUT/2
        float ax = 0.f, ay = 0.f;
        int cnt = min(e1[r] - e0[r], 64);
        int j = 0;
        for (; j + 4 <= cnt; j += 4) {
            int s0 = __shfl(sl[r], j), s1 = __shfl(sl[r], j + 1);
            int s2 = __shfl(sl[r], j + 2), s3 = __shfl(sl[r], j + 3);
            float w0 = __shfl(wl[r], j), w1 = __shfl(wl[r], j + 1);
            float w2 = __shfl(wl[r], j + 2), w3 = __shfl(wl[r], j + 3);
            ushort2 v0 = rows[(size_t)s0 * (3 * FOUT / 2) + lane];
            ushort2 v1 = rows[(size_t)s1 * (3 * FOUT / 2) + lane];
            ushort2 v2 = rows[(size_t)s2 * (3 * FOUT / 2) + lane];
            ushort2 v3 = rows[(size_t)s3 * (3 * FOUT / 2) + lane];
            ax += w0 * bf2f(v0.x); ay += w0 * bf2f(v0.y);
            ax += w1 * bf2f(v1.x); ay += w1 * bf2f(v1.y);
            ax += w2 * bf2f(v2.x); ay += w2 * bf2f(v2.y);
            ax += w3 * bf2f(v3.x); ay += w3 * bf2f(v3.y);
        }
        for (; j < cnt; ++j) {
            int s = __shfl(sl[r], j);
            float w = __shfl(wl[r], j);
            ushort2 v = rows[(size_t)s * (3 * FOUT / 2) + lane];
            ax += w * bf2f(v.x); ay += w * bf2f(v.y);
        }
        if (e0[r] + 64 < e1[r])
            gather_chunk(rows, 3 * FOUT / 2, col + (size_t)r * NEDGE, c_src + r * NNODE,
                         e0[r] + 64, e1[r], lane, ax, ay);
        float cd = c_dst[r * NNODE + wid];
        acc.x += cd * ax;
        acc.y += cd * ay;
    }
    out2[(size_t)wid * (FOUT / 2) + lane] = acc;
}

// ------------------------------------------------------------ MFMA GEMM
// C[M][N] = A[M][K](bf16) @ B, B pre-transposed [N][K] hi/lo bf16.
// acc += A*Bh + A*Bl. 128x128 tile, BK=32, 4 waves 2x2, 4x4 frags 16x16x32.
// EPI 0: C = relu(acc + bias) -> bf16.  EPI 1: C = acc -> bf16.

template <int K, int EPI>
__global__ __launch_bounds__(256)
void gemm_bf16(const unsigned short* __restrict__ A, const unsigned short* __restrict__ Bh,
               const unsigned short* __restrict__ Bl, const float* __restrict__ bias,
               unsigned short* __restrict__ C, int M, int N) {
    __shared__ unsigned short As[128][40];
    __shared__ unsigned short Bsh[128][40];
    __shared__ unsigned short Bsl[128][40];
    const int bm = blockIdx.x * 128;
    const int bn = blockIdx.y * 128;
    const int tid = threadIdx.x;
    const int lane = tid & 63;
    const int wv = tid >> 6;
    const int wm = (wv >> 1) * 64;
    const int wn = (wv & 1) * 64;

    const int srow = tid >> 1;        // 0..127
    const int scol = (tid & 1) * 16;  // shorts
    const size_t abase = (size_t)(bm + srow) * K + scol;
    const size_t bbase = (size_t)(bn + srow) * K + scol;
    const bool avalid = (bm + srow) < M;

    f32x4 acc[4][4] = {};

    for (int k0 = 0; k0 < K; k0 += 32) {
        uint4 z = make_uint4(0, 0, 0, 0);
        uint4 a0 = z, a1 = z;
        if (avalid) {
            a0 = *(const uint4*)&A[abase + k0];
            a1 = *(const uint4*)&A[abase + k0 + 8];
        }
        uint4 b0 = *(const uint4*)&Bh[bbase + k0];
        uint4 b1 = *(const uint4*)&Bh[bbase + k0 + 8];
        uint4 m0 = *(const uint4*)&Bl[bbase + k0];
        uint4 m1 = *(const uint4*)&Bl[bbase + k0 + 8];
        *(uint4*)&As[srow][scol] = a0;
        *(uint4*)&As[srow][scol + 8] = a1;
        *(uint4*)&Bsh[srow][scol] = b0;
        *(uint4*)&Bsh[srow][scol + 8] = b1;
        *(uint4*)&Bsl[srow][scol] = m0;
        *(uint4*)&Bsl[srow][scol + 8] = m1;
        __syncthreads();

        const int kb = (lane >> 4) * 8;
        const int fr = lane & 15;
        bf16x8 a[4], bh[4], bl[4];
#pragma unroll
        for (int i = 0; i < 4; ++i) {
            a[i] = *(const bf16x8*)&As[wm + i * 16 + fr][kb];
            bh[i] = *(const bf16x8*)&Bsh[wn + i * 16 + fr][kb];
            bl[i] = *(const bf16x8*)&Bsl[wn + i * 16 + fr][kb];
        }
#pragma unroll
        for (int mi = 0; mi < 4; ++mi)
#pragma unroll
            for (int ni = 0; ni < 4; ++ni) {
                acc[mi][ni] = __builtin_amdgcn_mfma_f32_16x16x32_bf16(a[mi], bh[ni], acc[mi][ni], 0, 0, 0);
                acc[mi][ni] = __builtin_amdgcn_mfma_f32_16x16x32_bf16(a[mi], bl[ni], acc[mi][ni], 0, 0, 0);
            }
        __syncthreads();
    }

    // epilogue: C/D map col=lane&15, row=(lane>>4)*4+reg
    const int cl = lane & 15;
    const int rl = (lane >> 4) * 4;
#pragma unroll
    for (int mi = 0; mi < 4; ++mi) {
#pragma unroll
        for (int ni = 0; ni < 4; ++ni) {
            const int gcol = bn + wn + ni * 16 + cl;
            float bv = (EPI == 0) ? bias[gcol] : 0.f;
#pragma unroll
            for (int rg = 0; rg < 4; ++rg) {
                const int grow = bm + wm + mi * 16 + rl + rg;
                if (grow < M) {
                    float v = acc[mi][ni][rg];
                    if (EPI == 0) v = fmaxf(v + bv, 0.f);
                    C[(size_t)grow * N + gcol] = f2bf(v);
                }
            }
        }
    }
}

// ---------------------------------------------------------------- launcher

extern "C" void kernel_launch(void* const* d_in, const int* in_sizes, int n_in,
                              void* d_out, int out_size, void* d_ws, size_t ws_size,
                              hipStream_t stream) {
    const float* x = (const float*)d_in[0];
    const int* src_b = (const int*)d_in[1];
    const int* dst_b = (const int*)d_in[2];
    const int* src_r = (const int*)d_in[3];
    const int* dst_r = (const int*)d_in[4];
    const int* src_j = (const int*)d_in[5];
    const int* dst_j = (const int*)d_in[6];
    const float* W1[3] = {(const float*)d_in[7], (const float*)d_in[11], (const float*)d_in[15]};
    const float* b1[3] = {(const float*)d_in[8], (const float*)d_in[12], (const float*)d_in[16]};
    const float* W2[3] = {(const float*)d_in[9], (const float*)d_in[13], (const float*)d_in[17]};
    const float* b2[3] = {(const float*)d_in[10], (const float*)d_in[14], (const float*)d_in[18]};
    float* out = (float*)d_out;

    char* w = (char*)d_ws;
    auto alloc = [&](size_t bytes) -> char* {
        char* p = w;
        w += (bytes + 255) & ~(size_t)255;
        return p;
    };
    // ~165 MB total (rank array dropped vs round 5)
    int* cnt = (int*)alloc((size_t)6 * NNODE * 4);  // cnt_src[3N] | cnt_dst[3N]
    int* cnt_src = cnt;
    int* cnt_dst = cnt + 3 * NNODE;
    float* c_src = (float*)alloc((size_t)3 * NNODE * 4);
    float* c_dst = (float*)alloc((size_t)3 * NNODE * 4);
    int* rp = (int*)alloc((size_t)3 * (NNODE + 1) * 4);
    int* tot = (int*)alloc((size_t)2 * 3 * NBUCK * 4);
    int* bb = (int*)alloc((size_t)2 * 3 * (NBUCK + 1) * 4);
    int* col = (int*)alloc((size_t)3 * NEDGE * 4);
    float* b1s = (float*)alloc(FHID * 4);
    float* b2s = (float*)alloc(FOUT * 4);
    unsigned short* xbf = (unsigned short*)alloc((size_t)NNODE * FIN * 2);        // [N][128] bf16
    unsigned short* aggcat = (unsigned short*)alloc((size_t)NNODE * 3 * FIN * 2); // [N][384] bf16
    unsigned short* ycat = aggcat;  // aliased: aggcat dead after L1 GEMM
    unsigned short* hb = (unsigned short*)alloc((size_t)NNODE * FHID * 2);        // [N][256] bf16

    // CSR-build scratch aliased inside aggcat (76.8 MB; dead until spmm1):
    char* sc = (char*)aggcat;
    int* bh_dst = (int*)sc;                          sc += (size_t)3 * NCHUNK * NBUCK * 4;  // 4.6 MB
    int* bh_src = (int*)sc;                          sc += (size_t)3 * NCHUNK * NBUCK * 4;  // 4.6 MB
    unsigned int* ebd = (unsigned int*)sc;           sc += (size_t)3 * NEDGE * 4;           // 6 MB
    unsigned char* ebs = (unsigned char*)sc;         sc += (size_t)3 * NEDGE;               // 1.5 MB

    // weight planes aliased over cnt (dead after norms); 786 KB < 2.4 MB
    unsigned short* w1h = (unsigned short*)cnt;            // [256][384]
    unsigned short* w1l = w1h + FHID * 3 * FIN;
    unsigned short* w2h = w1l + FHID * 3 * FIN;            // [384][256]
    unsigned short* w2l = w2h + 3 * FOUT * FHID;

    const int T = 256;

    // 1. graph preprocessing — atomic-free bucket-sorted CSR build
    csr_count<<<dim3(NCHUNK, 3), T, 0, stream>>>(
        src_b, dst_b, src_r, dst_r, src_j, dst_j, bh_dst, bh_src);
    csr_scan_chunks<<<dim3((2 * 3 * NBUCK + T - 1) / T), T, 0, stream>>>(bh_dst, bh_src, tot);
    csr_scan_buckets<<<dim3(2, 3), T, 0, stream>>>(tot, bb);
    csr_scatter<<<dim3(NCHUNK, 3), T, 0, stream>>>(
        src_b, dst_b, src_r, dst_r, src_j, dst_j, bh_dst, bh_src, bb, ebd, ebs);
    csr_finalize_dst<<<dim3(NBUCK, 3), T, 0, stream>>>(ebd, bb, cnt_dst, rp, col);
    csr_count_src<<<dim3(NBUCK, 3), T, 0, stream>>>(ebs, bb + 3 * (NBUCK + 1), cnt_src);
    norms_kernel<<<dim3((3 * NNODE + T - 1) / T), T, 0, stream>>>(cnt_src, cnt_dst, c_src, c_dst);

    // 2. operand prep (cnt region dead after norms)
    x2bf_kernel<<<dim3((NNODE * FIN / 4 + T - 1) / T), T, 0, stream>>>(
        (const float4*)x, (ushort4*)xbf, NNODE * FIN / 4);
    for (int r = 0; r < 3; ++r) {
        // W1_r [128][256] -> w1t[n][r*128+k], ldt=384
        wsplit_t<<<dim3((FIN * FHID + T - 1) / T), T, 0, stream>>>(
            W1[r], w1h, w1l, FIN, FHID, 3 * FIN, 0, r * FIN);
        // W2_r [256][128] -> w2t[r*128+n][k], ldt=256
        wsplit_t<<<dim3((FHID * FOUT + T - 1) / T), T, 0, stream>>>(
            W2[r], w2h, w2l, FHID, FOUT, FHID, r * FOUT, 0);
    }
    bias_sums<<<1, 256, 0, stream>>>(b1[0], b1[1], b1[2], b2[0], b2[1], b2[2], b1s, b2s);

    const dim3 spmm_grid((NNODE * 64 + T - 1) / T);

    // 3. layer 1: aggregate all relations -> aggcat [N,384] bf16, one GEMM -> h bf16
    spmm1_all<<<spmm_grid, T, 0, stream>>>(
        (const ushort2*)xbf, rp, col, c_src, c_dst, (ushort2*)aggcat);
    gemm_bf16<3 * FIN, 0><<<dim3((NNODE + 127) / 128, FHID / 128), 256, 0, stream>>>(
        aggcat, w1h, w1l, b1s, hb, NNODE, FHID);

    // 4. layer 2: one GEMM h @ [W2_b|W2_r|W2_j] -> ycat [N,384] bf16, aggregate -> out
    gemm_bf16<FHID, 1><<<dim3((NNODE + 127) / 128, (3 * FOUT) / 128), 256, 0, stream>>>(
        hb, w2h, w2l, nullptr, ycat, NNODE, 3 * FOUT);
    spmm2_all<<<spmm_grid, T, 0, stream>>>(
        (const ushort2*)ycat, rp, col, c_src, c_dst, (const float2*)b2s, (float2*)out);
}

// Round 7
// 487.520 us; speedup vs baseline: 2.8759x; 1.0954x over previous
//
#include <hip/hip_runtime.h>
#include <hip/hip_bf16.h>
#include <cstdint>

#define NNODE 100000
#define NEDGE 500000
#define FIN   128
#define FHID  256
#define FOUT  128

// bucket-sort CSR parameters
#define NBUCK  1563   // ceil(NNODE/64)
#define CHUNK  2048
#define NCHUNK 245    // ceil(NEDGE/CHUNK)

typedef __attribute__((ext_vector_type(8))) short bf16x8;
typedef __attribute__((ext_vector_type(4))) float f32x4;

// ---------------------------------------------------------------- bf16 utils

__device__ inline unsigned short f2bf(float f) {
    unsigned int u = __float_as_uint(f);
    unsigned int r = (u + 0x7FFF + ((u >> 16) & 1)) >> 16;
    return (unsigned short)r;
}
__device__ inline float bf2f(unsigned short s) {
    return __uint_as_float(((unsigned int)s) << 16);
}
__device__ inline void split2(float f, unsigned short& hi, unsigned short& lo) {
    hi = f2bf(f);
    lo = f2bf(f - bf2f(hi));
}

// ------------------------------------------------ atomic-free CSR build
// All coordination via LDS atomics; zero global atomics.

// P1: per-chunk LDS histograms over 64-node buckets (dst and src together)
__global__ __launch_bounds__(256)
void csr_count(const int* __restrict__ sb, const int* __restrict__ db,
               const int* __restrict__ sr, const int* __restrict__ dr,
               const int* __restrict__ sj, const int* __restrict__ dj,
               int* __restrict__ bh_dst, int* __restrict__ bh_src) {
    __shared__ int h1[NBUCK], h2[NBUCK];
    const int r = blockIdx.y, c = blockIdx.x, tid = threadIdx.x;
    const int* s = (r == 0) ? sb : (r == 1) ? sr : sj;
    const int* d = (r == 0) ? db : (r == 1) ? dr : dj;
    for (int i = tid; i < NBUCK; i += 256) { h1[i] = 0; h2[i] = 0; }
    __syncthreads();
    const int e0 = c * CHUNK;
#pragma unroll
    for (int i = 0; i < CHUNK / 256; ++i) {
        int e = e0 + i * 256 + tid;
        if (e < NEDGE) {
            atomicAdd(&h1[d[e] >> 6], 1);
            atomicAdd(&h2[s[e] >> 6], 1);
        }
    }
    __syncthreads();
    int* o1 = bh_dst + ((size_t)r * NCHUNK + c) * NBUCK;
    int* o2 = bh_src + ((size_t)r * NCHUNK + c) * NBUCK;
    for (int i = tid; i < NBUCK; i += 256) { o1[i] = h1[i]; o2[i] = h2[i]; }
}

// P2a: in-place exclusive scan over chunks (per bucket); emits bucket totals
__global__ void csr_scan_chunks(int* __restrict__ bh_dst, int* __restrict__ bh_src,
                                int* __restrict__ tot) {
    int idx = blockIdx.x * blockDim.x + threadIdx.x;
    if (idx >= 2 * 3 * NBUCK) return;
    int k = idx / (3 * NBUCK);
    int rem = idx - k * 3 * NBUCK;
    int r = rem / NBUCK;
    int b = rem - r * NBUCK;
    int* p = ((k == 0) ? bh_dst : bh_src) + (size_t)r * NCHUNK * NBUCK + b;
    int t = 0;
    int c = 0;
    for (; c + 4 <= NCHUNK; c += 4) {
        int v0 = p[0], v1 = p[NBUCK], v2 = p[2 * NBUCK], v3 = p[3 * NBUCK];
        p[0] = t; t += v0;
        p[NBUCK] = t; t += v1;
        p[2 * NBUCK] = t; t += v2;
        p[3 * NBUCK] = t; t += v3;
        p += 4 * NBUCK;
    }
    for (; c < NCHUNK; ++c) { int v = *p; *p = t; t += v; p += NBUCK; }
    tot[(k * 3 + r) * NBUCK + b] = t;
}

// P2b: exclusive scan over buckets -> bucket bases (incl. total at [NBUCK])
__global__ void csr_scan_buckets(const int* __restrict__ tot, int* __restrict__ bb) {
    const int k = blockIdx.x, r = blockIdx.y, tid = threadIdx.x;  // 256 thr
    const int base_in = (k * 3 + r) * NBUCK;
    const int base_out = (k * 3 + r) * (NBUCK + 1);
    int v[8];
    const int idx0 = tid * 8;
    int tsum = 0;
#pragma unroll
    for (int i = 0; i < 8; ++i) {
        int ii = idx0 + i;
        v[i] = (ii < NBUCK) ? tot[base_in + ii] : 0;
        tsum += v[i];
    }
    __shared__ int sm[256];
    sm[tid] = tsum;
    __syncthreads();
    for (int off = 1; off < 256; off <<= 1) {
        int t = 0;
        if (tid >= off) t = sm[tid - off];
        __syncthreads();
        sm[tid] += t;
        __syncthreads();
    }
    int run = sm[tid] - tsum;
#pragma unroll
    for (int i = 0; i < 8; ++i) {
        int ii = idx0 + i;
        if (ii <= NBUCK) bb[base_out + ii] = run;
        run += v[i];
    }
}

// P3: scatter edges into bucket-grouped buffers (LDS cursors, disjoint ranges)
__global__ __launch_bounds__(256)
void csr_scatter(const int* __restrict__ sb, const int* __restrict__ db,
                 const int* __restrict__ sr, const int* __restrict__ dr,
                 const int* __restrict__ sj, const int* __restrict__ dj,
                 const int* __restrict__ bh_dst, const int* __restrict__ bh_src,
                 const int* __restrict__ bb, unsigned int* __restrict__ ebd,
                 unsigned char* __restrict__ ebs) {
    __shared__ int cur1[NBUCK], cur2[NBUCK];
    const int r = blockIdx.y, c = blockIdx.x, tid = threadIdx.x;
    const int* s = (r == 0) ? sb : (r == 1) ? sr : sj;
    const int* d = (r == 0) ? db : (r == 1) ? dr : dj;
    const int* p1 = bh_dst + ((size_t)r * NCHUNK + c) * NBUCK;
    const int* p2 = bh_src + ((size_t)r * NCHUNK + c) * NBUCK;
    const int* bb1 = bb + r * (NBUCK + 1);              // dst section (k=0)
    const int* bb2 = bb + (3 + r) * (NBUCK + 1);        // src section (k=1)
    for (int i = tid; i < NBUCK; i += 256) {
        cur1[i] = bb1[i] + p1[i];
        cur2[i] = bb2[i] + p2[i];
    }
    __syncthreads();
    const int e0 = c * CHUNK;
#pragma unroll
    for (int i = 0; i < CHUNK / 256; ++i) {
        int e = e0 + i * 256 + tid;
        if (e < NEDGE) {
            int dv = d[e], sv = s[e];
            int q1 = atomicAdd(&cur1[dv >> 6], 1);
            ebd[(size_t)r * NEDGE + q1] = ((unsigned)(dv & 63) << 17) | (unsigned)sv;
            int q2 = atomicAdd(&cur2[sv >> 6], 1);
            ebs[(size_t)r * NEDGE + q2] = (unsigned char)(sv & 63);
        }
    }
}

// P4 (merged): dst finalize (rp, col, c_dst) + src count (c_src)
__global__ __launch_bounds__(256)
void csr_finalize(const unsigned int* __restrict__ ebd, const unsigned char* __restrict__ ebs,
                  const int* __restrict__ bb, int* __restrict__ rp, int* __restrict__ col,
                  float* __restrict__ c_src, float* __restrict__ c_dst) {
    __shared__ int hist[64], pref[64], cur[64];
    const int b = blockIdx.x, r = blockIdx.y, tid = threadIdx.x;
    const int* bb1 = bb + r * (NBUCK + 1);
    const int* bb2 = bb + (3 + r) * (NBUCK + 1);
    const int seg0 = bb1[b], seg1 = bb1[b + 1];
    if (tid < 64) hist[tid] = 0;
    __syncthreads();
    const unsigned int* eb = ebd + (size_t)r * NEDGE;
    for (int e = seg0 + tid; e < seg1; e += 256)
        atomicAdd(&hist[eb[e] >> 17], 1);
    __syncthreads();
    if (tid == 0) {
        int run = 0;
        for (int i = 0; i < 64; ++i) { pref[i] = run; run += hist[i]; }
    }
    __syncthreads();
    if (tid < 64) {
        int node = b * 64 + tid;
        if (node < NNODE) {
            rp[r * (NNODE + 1) + node] = seg0 + pref[tid];
            c_dst[r * NNODE + node] = rsqrtf((float)max(hist[tid], 1));
        }
        cur[tid] = seg0 + pref[tid];
    }
    if (b == 0 && tid == 0) rp[r * (NNODE + 1) + NNODE] = NEDGE;
    __syncthreads();
    for (int e = seg0 + tid; e < seg1; e += 256) {
        unsigned int key = eb[e];
        int pos = atomicAdd(&cur[key >> 17], 1);
        col[(size_t)r * NEDGE + pos] = (int)(key & 0x1FFFF);
    }
    // ---- src side (independent segment; reuse hist)
    __syncthreads();
    if (tid < 64) hist[tid] = 0;
    __syncthreads();
    const int t0 = bb2[b], t1 = bb2[b + 1];
    const unsigned char* es = ebs + (size_t)r * NEDGE;
    for (int e = t0 + tid; e < t1; e += 256)
        atomicAdd(&hist[es[e]], 1);
    __syncthreads();
    if (tid < 64) {
        int node = b * 64 + tid;
        if (node < NNODE) c_src[r * NNODE + node] = rsqrtf((float)max(hist[tid], 1));
    }
}

// ------------------------------------------- fused operand prep
// blocks [0,12500): x fp32->bf16 ; [12500,13268): 6 weight splits ; last: biases
#define XB_BLOCKS 12500   // NNODE*FIN/4/256

__global__ __launch_bounds__(256)
void prep_all(const float4* __restrict__ x4, ushort4* __restrict__ xb4,
              const float* __restrict__ W10, const float* __restrict__ W11,
              const float* __restrict__ W12, const float* __restrict__ W20,
              const float* __restrict__ W21, const float* __restrict__ W22,
              const float* __restrict__ b10, const float* __restrict__ b11,
              const float* __restrict__ b12, const float* __restrict__ b20,
              const float* __restrict__ b21, const float* __restrict__ b22,
              unsigned short* __restrict__ w1h, unsigned short* __restrict__ w1l,
              unsigned short* __restrict__ w2h, unsigned short* __restrict__ w2l,
              float* __restrict__ b1s, float* __restrict__ b2s) {
    int b = blockIdx.x;
    const int tid = threadIdx.x;
    if (b < XB_BLOCKS) {
        int i = b * 256 + tid;
        float4 v = x4[i];
        ushort4 o;
        o.x = f2bf(v.x); o.y = f2bf(v.y); o.z = f2bf(v.z); o.w = f2bf(v.w);
        xb4[i] = o;
        return;
    }
    b -= XB_BLOCKS;
    if (b < 768) {   // 6 tasks x 128 blocks; each task K*N = 32768
        int task = b >> 7;
        int i = ((b & 127) << 8) | tid;
        const float* W;
        unsigned short *th, *tl;
        int N, ldt, nbase, kbase;
        if (task < 3) {
            W = (task == 0) ? W10 : (task == 1) ? W11 : W12;
            th = w1h; tl = w1l; N = FHID; ldt = 3 * FIN; nbase = 0; kbase = task * FIN;
        } else {
            int r = task - 3;
            W = (r == 0) ? W20 : (r == 1) ? W21 : W22;
            th = w2h; tl = w2l; N = FOUT; ldt = FHID; nbase = r * FOUT; kbase = 0;
        }
        int k = i / N;
        int n = i - k * N;
        unsigned short hi, lo;
        split2(W[i], hi, lo);
        size_t o = (size_t)(nbase + n) * ldt + kbase + k;
        th[o] = hi;
        tl[o] = lo;
        return;
    }
    if (tid < FHID) b1s[tid] = b10[tid] + b11[tid] + b12[tid];
    if (tid < FOUT) b2s[tid] = b20[tid] + b21[tid] + b22[tid];
}

// --------------------------------------------------------------- SpMM (CSR)
// one wave per dst node; lane covers 2 feats (ushort2).
// Padded 8-group gathers: always issue groups of 8 loads back-to-back
// (slots past cnt read row sl_of_lane0-ish with weight forced to 0 — exact
// no-op, zero divergence, one latency round-trip per group).

__device__ inline void gather8(const ushort2* __restrict__ rows, int ldrow,
                               int sl, float wl, int cnt, int lane,
                               float& ax, float& ay) {
    for (int j = 0; j < cnt; j += 8) {
        float w[8];
        ushort2 v[8];
#pragma unroll
        for (int u = 0; u < 8; ++u) {
            int jj = (j + u) & 63;
            int s = __shfl(sl, jj);
            float ww = __shfl(wl, jj);
            w[u] = (j + u < cnt) ? ww : 0.f;
            v[u] = rows[(size_t)s * ldrow + lane];
        }
#pragma unroll
        for (int u = 0; u < 8; ++u) {
            ax += w[u] * bf2f(v[u].x);
            ay += w[u] * bf2f(v[u].y);
        }
    }
}

// deg > 64 fallback: reload 64 cols per chunk, same 8-group pattern
__device__ inline void gather_chunk(const ushort2* __restrict__ rows, int ldrow,
                                    const int* __restrict__ colp,
                                    const float* __restrict__ csrc, int e0, int e1,
                                    int lane, float& ax, float& ay) {
    for (int base = e0; base < e1; base += 64) {
        int cnt = min(64, e1 - base);
        int sl = (lane < cnt) ? colp[base + lane] : 0;
        float wl = (lane < cnt) ? csrc[sl] : 0.f;
        gather8(rows, ldrow, sl, wl, cnt, lane, ax, ay);
    }
}

__global__ __launch_bounds__(256)
void spmm1_all(const ushort2* __restrict__ xb, const int* __restrict__ rp,
               const int* __restrict__ col, const float* __restrict__ c_src,
               const float* __restrict__ c_dst, ushort2* __restrict__ agg) {
    int wid = (blockIdx.x * blockDim.x + threadIdx.x) >> 6;
    int lane = threadIdx.x & 63;
    if (wid >= NNODE) return;
    int e0[3], e1[3], sl[3];
    float wl[3];
#pragma unroll
    for (int r = 0; r < 3; ++r) {
        e0[r] = rp[r * (NNODE + 1) + wid];
        e1[r] = rp[r * (NNODE + 1) + wid + 1];
    }
#pragma unroll
    for (int r = 0; r < 3; ++r) {
        int cnt = min(e1[r] - e0[r], 64);
        sl[r] = (lane < cnt) ? col[r * NEDGE + e0[r] + lane] : 0;
    }
#pragma unroll
    for (int r = 0; r < 3; ++r) {
        int cnt = min(e1[r] - e0[r], 64);
        wl[r] = (lane < cnt) ? c_src[r * NNODE + sl[r]] : 0.f;
    }
#pragma unroll
    for (int r = 0; r < 3; ++r) {
        float ax = 0.f, ay = 0.f;
        int cnt = min(e1[r] - e0[r], 64);
        gather8(xb, FIN / 2, sl[r], wl[r], cnt, lane, ax, ay);
        if (e0[r] + 64 < e1[r])
            gather_chunk(xb, FIN / 2, col + (size_t)r * NEDGE, c_src + r * NNODE,
                         e0[r] + 64, e1[r], lane, ax, ay);
        float cd = c_dst[r * NNODE + wid];
        ushort2 o;
        o.x = f2bf(ax * cd);
        o.y = f2bf(ay * cd);
        agg[(size_t)wid * (3 * FIN / 2) + r * (FIN / 2) + lane] = o;  // [N][384] bf16
    }
}

__global__ __launch_bounds__(256)
void spmm2_all(const ushort2* __restrict__ yb, const int* __restrict__ rp,
               const int* __restrict__ col, const float* __restrict__ c_src,
               const float* __restrict__ c_dst, const float2* __restrict__ b2s2,
               float2* __restrict__ out2) {
    int wid = (blockIdx.x * blockDim.x + threadIdx.x) >> 6;
    int lane = threadIdx.x & 63;
    if (wid >= NNODE) return;
    int e0[3], e1[3], sl[3];
    float wl[3];
#pragma unroll
    for (int r = 0; r < 3; ++r) {
        e0[r] = rp[r * (NNODE + 1) + wid];
        e1[r] = rp[r * (NNODE + 1) + wid + 1];
    }
#pragma unroll
    for (int r = 0; r < 3; ++r) {
        int cnt = min(e1[r] - e0[r], 64);
        sl[r] = (lane < cnt) ? col[r * NEDGE + e0[r] + lane] : 0;
    }
#pragma unroll
    for (int r = 0; r < 3; ++r) {
        int cnt = min(e1[r] - e0[r], 64);
        wl[r] = (lane < cnt) ? c_src[r * NNODE + sl[r]] : 0.f;
    }
    float2 acc = b2s2[lane];
#pragma unroll
    for (int r = 0; r < 3; ++r) {
        const ushort2* rows = yb + r * (FOUT / 2);  // row stride 3*FOUT/2
        float ax = 0.f, ay = 0.f;
        int cnt = min(e1[r] - e0[r], 64);
        gather8(rows, 3 * FOUT / 2, sl[r], wl[r], cnt, lane, ax, ay);
        if (e0[r] + 64 < e1[r])
            gather_chunk(rows, 3 * FOUT / 2, col + (size_t)r * NEDGE, c_src + r * NNODE,
                         e0[r] + 64, e1[r], lane, ax, ay);
        float cd = c_dst[r * NNODE + wid];
        acc.x += cd * ax;
        acc.y += cd * ay;
    }
    out2[(size_t)wid * (FOUT / 2) + lane] = acc;
}

// ------------------------------------------------------------ MFMA GEMM
// C[M][N] = A[M][K](bf16) @ B, B pre-transposed [N][K] hi/lo bf16.
// acc += A*Bh + A*Bl. 128x128 tile, BK=32, 4 waves 2x2, 4x4 frags 16x16x32.
// EPI 0: C = relu(acc + bias) -> bf16.  EPI 1: C = acc -> bf16.

template <int K, int EPI>
__global__ __launch_bounds__(256)
void gemm_bf16(const unsigned short* __restrict__ A, const unsigned short* __restrict__ Bh,
               const unsigned short* __restrict__ Bl, const float* __restrict__ bias,
               unsigned short* __restrict__ C, int M, int N) {
    __shared__ unsigned short As[128][40];
    __shared__ unsigned short Bsh[128][40];
    __shared__ unsigned short Bsl[128][40];
    const int bm = blockIdx.x * 128;
    const int bn = blockIdx.y * 128;
    const int tid = threadIdx.x;
    const int lane = tid & 63;
    const int wv = tid >> 6;
    const int wm = (wv >> 1) * 64;
    const int wn = (wv & 1) * 64;

    const int srow = tid >> 1;        // 0..127
    const int scol = (tid & 1) * 16;  // shorts
    const size_t abase = (size_t)(bm + srow) * K + scol;
    const size_t bbase = (size_t)(bn + srow) * K + scol;
    const bool avalid = (bm + srow) < M;

    f32x4 acc[4][4] = {};

    for (int k0 = 0; k0 < K; k0 += 32) {
        uint4 z = make_uint4(0, 0, 0, 0);
        uint4 a0 = z, a1 = z;
        if (avalid) {
            a0 = *(const uint4*)&A[abase + k0];
            a1 = *(const uint4*)&A[abase + k0 + 8];
        }
        uint4 b0 = *(const uint4*)&Bh[bbase + k0];
        uint4 b1 = *(const uint4*)&Bh[bbase + k0 + 8];
        uint4 m0 = *(const uint4*)&Bl[bbase + k0];
        uint4 m1 = *(const uint4*)&Bl[bbase + k0 + 8];
        *(uint4*)&As[srow][scol] = a0;
        *(uint4*)&As[srow][scol + 8] = a1;
        *(uint4*)&Bsh[srow][scol] = b0;
        *(uint4*)&Bsh[srow][scol + 8] = b1;
        *(uint4*)&Bsl[srow][scol] = m0;
        *(uint4*)&Bsl[srow][scol + 8] = m1;
        __syncthreads();

        const int kb = (lane >> 4) * 8;
        const int fr = lane & 15;
        bf16x8 a[4], bh[4], bl[4];
#pragma unroll
        for (int i = 0; i < 4; ++i) {
            a[i] = *(const bf16x8*)&As[wm + i * 16 + fr][kb];
            bh[i] = *(const bf16x8*)&Bsh[wn + i * 16 + fr][kb];
            bl[i] = *(const bf16x8*)&Bsl[wn + i * 16 + fr][kb];
        }
#pragma unroll
        for (int mi = 0; mi < 4; ++mi)
#pragma unroll
            for (int ni = 0; ni < 4; ++ni) {
                acc[mi][ni] = __builtin_amdgcn_mfma_f32_16x16x32_bf16(a[mi], bh[ni], acc[mi][ni], 0, 0, 0);
                acc[mi][ni] = __builtin_amdgcn_mfma_f32_16x16x32_bf16(a[mi], bl[ni], acc[mi][ni], 0, 0, 0);
            }
        __syncthreads();
    }

    // epilogue: C/D map col=lane&15, row=(lane>>4)*4+reg
    const int cl = lane & 15;
    const int rl = (lane >> 4) * 4;
#pragma unroll
    for (int mi = 0; mi < 4; ++mi) {
#pragma unroll
        for (int ni = 0; ni < 4; ++ni) {
            const int gcol = bn + wn + ni * 16 + cl;
            float bv = (EPI == 0) ? bias[gcol] : 0.f;
#pragma unroll
            for (int rg = 0; rg < 4; ++rg) {
                const int grow = bm + wm + mi * 16 + rl + rg;
                if (grow < M) {
                    float v = acc[mi][ni][rg];
                    if (EPI == 0) v = fmaxf(v + bv, 0.f);
                    C[(size_t)grow * N + gcol] = f2bf(v);
                }
            }
        }
    }
}

// ---------------------------------------------------------------- launcher

extern "C" void kernel_launch(void* const* d_in, const int* in_sizes, int n_in,
                              void* d_out, int out_size, void* d_ws, size_t ws_size,
                              hipStream_t stream) {
    const float* x = (const float*)d_in[0];
    const int* src_b = (const int*)d_in[1];
    const int* dst_b = (const int*)d_in[2];
    const int* src_r = (const int*)d_in[3];
    const int* dst_r = (const int*)d_in[4];
    const int* src_j = (const int*)d_in[5];
    const int* dst_j = (const int*)d_in[6];
    const float* W1[3] = {(const float*)d_in[7], (const float*)d_in[11], (const float*)d_in[15]};
    const float* b1[3] = {(const float*)d_in[8], (const float*)d_in[12], (const float*)d_in[16]};
    const float* W2[3] = {(const float*)d_in[9], (const float*)d_in[13], (const float*)d_in[17]};
    const float* b2[3] = {(const float*)d_in[10], (const float*)d_in[14], (const float*)d_in[18]};
    float* out = (float*)d_out;

    char* w = (char*)d_ws;
    auto alloc = [&](size_t bytes) -> char* {
        char* p = w;
        w += (bytes + 255) & ~(size_t)255;
        return p;
    };
    float* c_src = (float*)alloc((size_t)3 * NNODE * 4);
    float* c_dst = (float*)alloc((size_t)3 * NNODE * 4);
    int* rp = (int*)alloc((size_t)3 * (NNODE + 1) * 4);
    int* tot = (int*)alloc((size_t)2 * 3 * NBUCK * 4);
    int* bb = (int*)alloc((size_t)2 * 3 * (NBUCK + 1) * 4);
    int* col = (int*)alloc((size_t)3 * NEDGE * 4);
    float* b1s = (float*)alloc(FHID * 4);
    float* b2s = (float*)alloc(FOUT * 4);
    unsigned short* wpl = (unsigned short*)alloc((size_t)4 * 98304 * 2);  // 786 KB
    unsigned short* w1h = wpl;                     // [256][384]
    unsigned short* w1l = w1h + FHID * 3 * FIN;
    unsigned short* w2h = w1l + FHID * 3 * FIN;    // [384][256]
    unsigned short* w2l = w2h + 3 * FOUT * FHID;
    unsigned short* xbf = (unsigned short*)alloc((size_t)NNODE * FIN * 2);        // [N][128] bf16
    unsigned short* aggcat = (unsigned short*)alloc((size_t)NNODE * 3 * FIN * 2); // [N][384] bf16
    unsigned short* ycat = aggcat;  // aliased: aggcat dead after L1 GEMM
    unsigned short* hb = (unsigned short*)alloc((size_t)NNODE * FHID * 2);        // [N][256] bf16

    // CSR-build scratch aliased inside aggcat (76.8 MB; dead until spmm1):
    char* sc = (char*)aggcat;
    int* bh_dst = (int*)sc;                  sc += (size_t)3 * NCHUNK * NBUCK * 4;  // 4.6 MB
    int* bh_src = (int*)sc;                  sc += (size_t)3 * NCHUNK * NBUCK * 4;  // 4.6 MB
    unsigned int* ebd = (unsigned int*)sc;   sc += (size_t)3 * NEDGE * 4;           // 6 MB
    unsigned char* ebs = (unsigned char*)sc; sc += (size_t)3 * NEDGE;               // 1.5 MB

    const int T = 256;

    // 1. atomic-free bucket-sorted CSR build (c_src/c_dst/rp/col all direct)
    csr_count<<<dim3(NCHUNK, 3), T, 0, stream>>>(
        src_b, dst_b, src_r, dst_r, src_j, dst_j, bh_dst, bh_src);
    csr_scan_chunks<<<dim3((2 * 3 * NBUCK + T - 1) / T), T, 0, stream>>>(bh_dst, bh_src, tot);
    csr_scan_buckets<<<dim3(2, 3), T, 0, stream>>>(tot, bb);
    csr_scatter<<<dim3(NCHUNK, 3), T, 0, stream>>>(
        src_b, dst_b, src_r, dst_r, src_j, dst_j, bh_dst, bh_src, bb, ebd, ebs);
    csr_finalize<<<dim3(NBUCK, 3), T, 0, stream>>>(ebd, ebs, bb, rp, col, c_src, c_dst);

    // 2. fused operand prep (x->bf16, 6 weight splits, bias sums)
    prep_all<<<dim3(XB_BLOCKS + 768 + 1), T, 0, stream>>>(
        (const float4*)x, (ushort4*)xbf,
        W1[0], W1[1], W1[2], W2[0], W2[1], W2[2],
        b1[0], b1[1], b1[2], b2[0], b2[1], b2[2],
        w1h, w1l, w2h, w2l, b1s, b2s);

    const dim3 spmm_grid((NNODE * 64 + T - 1) / T);

    // 3. layer 1: aggregate all relations -> aggcat [N,384] bf16, one GEMM -> h bf16
    spmm1_all<<<spmm_grid, T, 0, stream>>>(
        (const ushort2*)xbf, rp, col, c_src, c_dst, (ushort2*)aggcat);
    gemm_bf16<3 * FIN, 0><<<dim3((NNODE + 127) / 128, FHID / 128), 256, 0, stream>>>(
        aggcat, w1h, w1l, b1s, hb, NNODE, FHID);

    // 4. layer 2: one GEMM h @ [W2_b|W2_r|W2_j] -> ycat [N,384] bf16, aggregate -> out
    gemm_bf16<FHID, 1><<<dim3((NNODE + 127) / 128, (3 * FOUT) / 128), 256, 0, stream>>>(
        hb, w2h, w2l, nullptr, ycat, NNODE, 3 * FOUT);
    spmm2_all<<<spmm_grid, T, 0, stream>>>(
        (const ushort2*)ycat, rp, col, c_src, c_dst, (const float2*)b2s, (float2*)out);
}